// Round 7
// baseline (236.988 us; speedup 1.0000x reference)
//
#include <hip/hip_runtime.h>

// VSGNet fused pipeline — fp32 in/out, bf16 MFMA compute.
// B=64 P=16 L=16 D=1024 SP=32 PROJ=512 ACT=29, C=16384.
// R6 counters: relu_proj2 55us, VGPR=36, latency-stalled on 16 strided dword
// loads + 24 f2b per k-iter. R7: prep kernel pre-converts activations to bf16
// and pre-transposes Wvis/Who/Woh to bf16 [n][k]; all GEMM k-loops become pure
// 16B-load + MFMA. Needs ~15.7MB ws -> runtime branch on ws_size (fallback =
// round-6 path).

typedef unsigned short u16;   // bf16 bits
typedef short s16x8 __attribute__((ext_vector_type(8)));
typedef float f32x4 __attribute__((ext_vector_type(4)));

__device__ __forceinline__ u16 f2b(float f) {
    union { float f; unsigned int i; } v; v.f = f;
    unsigned int r = (v.i + 0x7fffu + ((v.i >> 16) & 1u)) >> 16;  // RNE
    return (u16)r;
}
__device__ __forceinline__ float b2f(u16 u) {
    union { float f; unsigned int i; } v; v.i = ((unsigned int)u) << 16; return v.f;
}
// load 8 consecutive fp32, convert to bf16 MFMA fragment
__device__ __forceinline__ s16x8 ld8(const float* p) {
    float4 a = *(const float4*)p;
    float4 b = *(const float4*)(p + 4);
    s16x8 r;
    r[0] = (short)f2b(a.x); r[1] = (short)f2b(a.y);
    r[2] = (short)f2b(a.z); r[3] = (short)f2b(a.w);
    r[4] = (short)f2b(b.x); r[5] = (short)f2b(b.y);
    r[6] = (short)f2b(b.z); r[7] = (short)f2b(b.w);
    return r;
}
// build B-fragment from row-major fp32 W[k][n]: lane col fixed, 8 strided loads
__device__ __forceinline__ s16x8 ldb(const float* p, int ldw) {
    s16x8 r;
#pragma unroll
    for (int j = 0; j < 8; j++) r[j] = (short)f2b(p[(size_t)j * ldw]);
    return r;
}

// ---------------- workspace layout (bytes) ----------------
// base region (both paths), total 2,973,696:
#define OFF_WSPATT 0u         // [512][32]  bf16
#define OFF_WREFT  32768u     // [32][512]  bf16 (rows 29..31 zero)
#define OFF_WATTT  65536u     // [32][512]  bf16
#define OFF_WGT    98304u     // [32][2048] bf16
#define OFF_PP     229376u    // [1024][512] bf16
#define OFF_PO     1277952u   // [1024][512] bf16
#define OFF_PC     2326528u   // [64][512]  bf16
#define OFF_ADJ    2392064u   // [16384] f32
#define OFF_HP     2457600u   // [1024][32] f32
#define OFF_HOF    2588672u   // [1024][32] f32
#define OFF_YH     2719744u   // [1024][32] f32
#define OFF_ZO     2850816u   // [960][32]  f32
#define ZERO_OFF   2457600u
#define ZERO_LEN   516096u
// fast-path extension (bf16 pre-converted operands):
#define OFF_WVIST2 2973696u   // [512][3072] bf16 (n-major, k contiguous)
#define OFF_WHOT2  6119424u   // [1024][1024] bf16
#define OFF_WOHT2  8216576u   // [1024][1024] bf16
#define OFF_PEOB   10313728u  // [1024][1024] bf16  people
#define OFF_OBJB   12410880u  // [1024][1024] bf16  objects
#define OFF_CTXB   14508032u  // [64][1024]  bf16  context
#define OFF_SPATB  14639104u  // [16384][32] bf16  spatial
#define WS_FAST_NEED 15687680u

// ---------------- small-weight transposes (fp32 src -> bf16 ws) -------------
__global__ __launch_bounds__(256) void transpose_small(
    const float* __restrict__ Wspat, const float* __restrict__ Wref,
    const float* __restrict__ Watt, const float* __restrict__ Wg,
    u16* __restrict__ WspatT, u16* __restrict__ WrefT,
    u16* __restrict__ WattT, u16* __restrict__ WgT)
{
    int g = blockIdx.x * 256 + threadIdx.x;
    int gsz = gridDim.x * 256;
    for (int i = g; i < 512 * 32; i += gsz) {
        int n = i >> 5, k = i & 31;
        WspatT[i] = f2b(Wspat[k * 512 + n]);
    }
    for (int i = g; i < 32 * 512; i += gsz) {
        int n = i >> 9, k = i & 511;
        WrefT[i] = (n < 29) ? f2b(Wref[k * 29 + n]) : (u16)0;
    }
    for (int i = g; i < 32 * 512; i += gsz) {
        int n = i >> 9, k = i & 511;
        WattT[i] = (n < 29) ? f2b(Watt[k * 29 + n]) : (u16)0;
    }
    for (int i = g; i < 32 * 2048; i += gsz) {
        int n = i >> 11, k = i & 2047;
        WgT[i] = (n < 29) ? f2b(Wg[k * 29 + n]) : (u16)0;
    }
}

// ---------------- fast-path prep: bf16 converts + big transposes ------------
__global__ __launch_bounds__(256) void prep_fast(
    const float* __restrict__ people, const float* __restrict__ objects,
    const float* __restrict__ context, const float* __restrict__ spatial,
    const float* __restrict__ Wvis, const float* __restrict__ Who,
    const float* __restrict__ Woh,
    u16* __restrict__ peoB, u16* __restrict__ objB, u16* __restrict__ ctxB,
    u16* __restrict__ spatB, u16* __restrict__ WvisT, u16* __restrict__ WhoT,
    u16* __restrict__ WohT)
{
    int g = blockIdx.x * 256 + threadIdx.x;
    int gsz = gridDim.x * 256;
    for (int i = g; i < 1048576; i += gsz) peoB[i] = f2b(people[i]);
    for (int i = g; i < 1048576; i += gsz) objB[i] = f2b(objects[i]);
    for (int i = g; i < 65536; i += gsz)   ctxB[i] = f2b(context[i]);
    for (int i = g; i < 524288; i += gsz)  spatB[i] = f2b(spatial[i]);
    for (int i = g; i < 512 * 3072; i += gsz) {      // WvisT[n][k] <- Wvis[k][n]
        int n = i / 3072, k = i - n * 3072;
        WvisT[i] = f2b(Wvis[(size_t)k * 512 + n]);
    }
    for (int i = g; i < 1048576; i += gsz) {         // WhoT[n][k] <- Who[k][n]
        int n = i >> 10, k = i & 1023;
        WhoT[i] = f2b(Who[(size_t)k * 1024 + n]);
    }
    for (int i = g; i < 1048576; i += gsz) {
        int n = i >> 10, k = i & 1023;
        WohT[i] = f2b(Woh[(size_t)k * 1024 + n]);
    }
}

// ======================= FAST-PATH GEMM KERNELS =============================
// ---- batched: {Pp,Po,Pc} = {peoB,objB,ctxB} @ WvisT slices. All bf16 16B loads.
__global__ __launch_bounds__(256) void gemm3f(
    const u16* __restrict__ peoB, const u16* __restrict__ objB,
    const u16* __restrict__ ctxB, const u16* __restrict__ WvisT,
    u16* __restrict__ Pp, u16* __restrict__ Po, u16* __restrict__ Pc)
{
    int t = threadIdx.x;
    int lane = t & 63, w = t >> 6;
    int l16 = lane & 15, q = lane >> 4;
    int wy = w >> 1, wx = w & 1;
    int ty = blockIdx.y;
    const u16* A; u16* outB; int koff, bm;
    if (ty < 16)      { A = peoB; outB = Pp; koff = 0;    bm = ty * 64; }
    else if (ty < 32) { A = objB; outB = Po; koff = 1024; bm = (ty - 16) * 64; }
    else              { A = ctxB; outB = Pc; koff = 2048; bm = 0; }
    int bn = blockIdx.x * 64;

    const u16* ap0 = A + (size_t)(bm + wy * 32 + l16) * 1024 + q * 8;
    const u16* ap1 = ap0 + (size_t)16 * 1024;
    const u16* bp0 = WvisT + (size_t)(bn + wx * 32 + l16) * 3072 + koff + q * 8;
    const u16* bp1 = bp0 + (size_t)16 * 3072;

    f32x4 acc00 = {0,0,0,0}, acc01 = {0,0,0,0}, acc10 = {0,0,0,0}, acc11 = {0,0,0,0};
    for (int k0 = 0; k0 < 1024; k0 += 32) {
        s16x8 a0 = *(const s16x8*)ap0; ap0 += 32;
        s16x8 a1 = *(const s16x8*)ap1; ap1 += 32;
        s16x8 b0 = *(const s16x8*)bp0; bp0 += 32;
        s16x8 b1 = *(const s16x8*)bp1; bp1 += 32;
        acc00 = __builtin_amdgcn_mfma_f32_16x16x32_bf16(a0, b0, acc00, 0, 0, 0);
        acc01 = __builtin_amdgcn_mfma_f32_16x16x32_bf16(a0, b1, acc01, 0, 0, 0);
        acc10 = __builtin_amdgcn_mfma_f32_16x16x32_bf16(a1, b0, acc10, 0, 0, 0);
        acc11 = __builtin_amdgcn_mfma_f32_16x16x32_bf16(a1, b1, acc11, 0, 0, 0);
    }
    f32x4 accs[2][2] = {{acc00, acc01}, {acc10, acc11}};
#pragma unroll
    for (int ii = 0; ii < 2; ii++)
#pragma unroll
        for (int jj = 0; jj < 2; jj++) {
            int col = bn + wx * 32 + jj * 16 + l16;
#pragma unroll
            for (int r = 0; r < 4; r++) {
                int row = bm + wy * 32 + ii * 16 + q * 4 + r;
                outB[(size_t)row * 512 + col] = f2b(accs[ii][jj][r]);
            }
        }
}

// ---- batched split relu-projection, all-bf16 stage 1 ------------------------
__global__ __launch_bounds__(256) void relu_proj2f(
    const u16* __restrict__ peoB, const u16* __restrict__ objB,
    const u16* __restrict__ WhoT, const float* __restrict__ Who_b,
    const u16* __restrict__ WohT, const float* __restrict__ Woh_b,
    const u16* __restrict__ WgT,
    float* __restrict__ Yh, float* __restrict__ Zo)
{
    __shared__ u16 T[32][72];
    int z = blockIdx.z;
    int m0 = blockIdx.x * 32;
    if (z && m0 >= 960) return;
    const u16* A    = z ? objB : peoB;
    const u16* W1T  = z ? WohT : WhoT;
    const float* bb = z ? Woh_b : Who_b;
    const u16* Wg2  = z ? WgT : WgT + 1024;
    float* U        = z ? Zo : Yh;

    int t = threadIdx.x;
    int lane = t & 63, w = t >> 6;
    int l16 = lane & 15, q = lane >> 4;
    int wy = w >> 1, wx = w & 1;
    int nb = blockIdx.y * 64;

    int r = m0 + wy * 16 + l16;
    if (z) r = (r / 15) * 16 + (r % 15) + 1;
    const u16* arow = A + (size_t)r * 1024;
    const u16* bp0 = W1T + (size_t)(nb + wx * 32 + l16) * 1024 + q * 8;
    const u16* bp1 = bp0 + (size_t)16 * 1024;

    f32x4 acc0 = {0,0,0,0}, acc1 = {0,0,0,0};
    for (int k0 = 0; k0 < 1024; k0 += 32) {
        s16x8 a = *(const s16x8*)(arow + k0 + q * 8);
        s16x8 b0 = *(const s16x8*)bp0; bp0 += 32;
        s16x8 b1 = *(const s16x8*)bp1; bp1 += 32;
        acc0 = __builtin_amdgcn_mfma_f32_16x16x32_bf16(a, b0, acc0, 0, 0, 0);
        acc1 = __builtin_amdgcn_mfma_f32_16x16x32_bf16(a, b1, acc1, 0, 0, 0);
    }
#pragma unroll
    for (int jj = 0; jj < 2; jj++) {
        int col = wx * 32 + jj * 16 + l16;
        float bv = bb[nb + col];
#pragma unroll
        for (int rr = 0; rr < 4; rr++) {
            float v = (jj ? acc1[rr] : acc0[rr]) + bv;
            T[wy * 16 + q * 4 + rr][col] = f2b(fmaxf(v, 0.f));
        }
    }
    __syncthreads();

    int rt = w >> 1, ct = w & 1;
    f32x4 acc = {0,0,0,0};
#pragma unroll
    for (int kk = 0; kk < 64; kk += 32) {
        s16x8 a = *(const s16x8*)(&T[rt * 16 + l16][kk + q * 8]);
        s16x8 b = *(const s16x8*)(Wg2 + (size_t)(ct * 16 + l16) * 2048 + nb + kk + q * 8);
        acc = __builtin_amdgcn_mfma_f32_16x16x32_bf16(a, b, acc, 0, 0, 0);
    }
    int col = ct * 16 + l16;
#pragma unroll
    for (int rr = 0; rr < 4; rr++)
        atomicAdd(&U[(size_t)(m0 + rt * 16 + q * 4 + rr) * 32 + col], acc[rr]);
}

// ---- batched split-K Hp/HoF, bf16 A ----------------------------------------
__global__ __launch_bounds__(256) void gemm_bt32f(
    const u16* __restrict__ peoB, const u16* __restrict__ objB,
    const u16* __restrict__ WgT, float* __restrict__ Hp, float* __restrict__ HoF)
{
    int z = blockIdx.z;
    const u16* A  = z ? objB : peoB;
    const u16* BT = z ? WgT + 1024 : WgT;
    float* outF   = z ? HoF : Hp;
    int t = threadIdx.x, lane = t & 63, w = t >> 6;
    int l16 = lane & 15, q = lane >> 4;
    int bm = blockIdx.x * 128 + w * 32;
    int kb = blockIdx.y * 128;
    const u16* ap0 = A + (size_t)(bm + l16) * 1024 + kb + q * 8;
    const u16* ap1 = A + (size_t)(bm + 16 + l16) * 1024 + kb + q * 8;
    const u16* bp0 = BT + (size_t)l16 * 2048 + kb + q * 8;
    const u16* bp1 = BT + (size_t)(16 + l16) * 2048 + kb + q * 8;
    f32x4 acc00 = {0,0,0,0}, acc01 = {0,0,0,0}, acc10 = {0,0,0,0}, acc11 = {0,0,0,0};
    for (int k = 0; k < 128; k += 32) {
        s16x8 a0 = *(const s16x8*)ap0; ap0 += 32;
        s16x8 a1 = *(const s16x8*)ap1; ap1 += 32;
        s16x8 b0 = *(const s16x8*)bp0; bp0 += 32;
        s16x8 b1 = *(const s16x8*)bp1; bp1 += 32;
        acc00 = __builtin_amdgcn_mfma_f32_16x16x32_bf16(a0, b0, acc00, 0, 0, 0);
        acc01 = __builtin_amdgcn_mfma_f32_16x16x32_bf16(a0, b1, acc01, 0, 0, 0);
        acc10 = __builtin_amdgcn_mfma_f32_16x16x32_bf16(a1, b0, acc10, 0, 0, 0);
        acc11 = __builtin_amdgcn_mfma_f32_16x16x32_bf16(a1, b1, acc11, 0, 0, 0);
    }
    f32x4 accs[2][2] = {{acc00, acc01}, {acc10, acc11}};
#pragma unroll
    for (int ii = 0; ii < 2; ii++)
#pragma unroll
        for (int jj = 0; jj < 2; jj++)
#pragma unroll
            for (int r = 0; r < 4; r++)
                atomicAdd(&outF[(size_t)(bm + ii * 16 + q * 4 + r) * 32 + jj * 16 + l16],
                          accs[ii][jj][r]);
}

// ======================= FALLBACK (round-6) KERNELS =========================
__global__ __launch_bounds__(256) void gemm3(
    const float* __restrict__ people, const float* __restrict__ objects,
    const float* __restrict__ context, const float* __restrict__ Wvis,
    u16* __restrict__ Pp, u16* __restrict__ Po, u16* __restrict__ Pc)
{
    int t = threadIdx.x;
    int lane = t & 63, w = t >> 6;
    int l16 = lane & 15, q = lane >> 4;
    int wy = w >> 1, wx = w & 1;
    int ty = blockIdx.y;
    const float* A; u16* outB; const float* W; int bm;
    if (ty < 16)      { A = people;  outB = Pp; W = Wvis;                      bm = ty * 64; }
    else if (ty < 32) { A = objects; outB = Po; W = Wvis + (size_t)1024 * 512; bm = (ty - 16) * 64; }
    else              { A = context; outB = Pc; W = Wvis + (size_t)2048 * 512; bm = 0; }
    int bn = blockIdx.x * 64;

    const float* ap0 = A + (size_t)(bm + wy * 32 + l16) * 1024 + q * 8;
    const float* ap1 = ap0 + (size_t)16 * 1024;
    const float* wp0 = W + (size_t)(q * 8) * 512 + bn + wx * 32 + l16;
    const float* wp1 = wp0 + 16;

    f32x4 acc00 = {0,0,0,0}, acc01 = {0,0,0,0}, acc10 = {0,0,0,0}, acc11 = {0,0,0,0};
    for (int k0 = 0; k0 < 1024; k0 += 32) {
        s16x8 a0 = ld8(ap0); ap0 += 32;
        s16x8 a1 = ld8(ap1); ap1 += 32;
        s16x8 b0 = ldb(wp0, 512); wp0 += (size_t)32 * 512;
        s16x8 b1 = ldb(wp1, 512); wp1 += (size_t)32 * 512;
        acc00 = __builtin_amdgcn_mfma_f32_16x16x32_bf16(a0, b0, acc00, 0, 0, 0);
        acc01 = __builtin_amdgcn_mfma_f32_16x16x32_bf16(a0, b1, acc01, 0, 0, 0);
        acc10 = __builtin_amdgcn_mfma_f32_16x16x32_bf16(a1, b0, acc10, 0, 0, 0);
        acc11 = __builtin_amdgcn_mfma_f32_16x16x32_bf16(a1, b1, acc11, 0, 0, 0);
    }
    f32x4 accs[2][2] = {{acc00, acc01}, {acc10, acc11}};
#pragma unroll
    for (int ii = 0; ii < 2; ii++)
#pragma unroll
        for (int jj = 0; jj < 2; jj++) {
            int col = bn + wx * 32 + jj * 16 + l16;
#pragma unroll
            for (int r = 0; r < 4; r++) {
                int row = bm + wy * 32 + ii * 16 + q * 4 + r;
                outB[(size_t)row * 512 + col] = f2b(accs[ii][jj][r]);
            }
        }
}

__global__ __launch_bounds__(256) void relu_proj2(
    const float* __restrict__ people, const float* __restrict__ objects,
    const float* __restrict__ Who, const float* __restrict__ Who_b,
    const float* __restrict__ Woh, const float* __restrict__ Woh_b,
    const u16* __restrict__ WgT,
    float* __restrict__ Yh, float* __restrict__ Zo)
{
    __shared__ u16 T[32][72];
    int z = blockIdx.z;
    int m0 = blockIdx.x * 32;
    if (z && m0 >= 960) return;
    const float* A  = z ? objects : people;
    const float* W1 = z ? Woh : Who;
    const float* bb = z ? Woh_b : Who_b;
    const u16* Wg2  = z ? WgT : WgT + 1024;
    float* U        = z ? Zo : Yh;

    int t = threadIdx.x;
    int lane = t & 63, w = t >> 6;
    int l16 = lane & 15, q = lane >> 4;
    int wy = w >> 1, wx = w & 1;
    int nb = blockIdx.y * 64;

    int r = m0 + wy * 16 + l16;
    if (z) r = (r / 15) * 16 + (r % 15) + 1;
    const float* arow = A + (size_t)r * 1024;
    const float* wp0 = W1 + (size_t)(q * 8) * 1024 + nb + wx * 32 + l16;
    const float* wp1 = wp0 + 16;

    f32x4 acc0 = {0,0,0,0}, acc1 = {0,0,0,0};
    for (int k0 = 0; k0 < 1024; k0 += 32) {
        s16x8 a = ld8(arow + k0 + q * 8);
        s16x8 b0 = ldb(wp0, 1024); wp0 += (size_t)32 * 1024;
        s16x8 b1 = ldb(wp1, 1024); wp1 += (size_t)32 * 1024;
        acc0 = __builtin_amdgcn_mfma_f32_16x16x32_bf16(a, b0, acc0, 0, 0, 0);
        acc1 = __builtin_amdgcn_mfma_f32_16x16x32_bf16(a, b1, acc1, 0, 0, 0);
    }
#pragma unroll
    for (int jj = 0; jj < 2; jj++) {
        int col = wx * 32 + jj * 16 + l16;
        float bv = bb[nb + col];
#pragma unroll
        for (int rr = 0; rr < 4; rr++) {
            float v = (jj ? acc1[rr] : acc0[rr]) + bv;
            T[wy * 16 + q * 4 + rr][col] = f2b(fmaxf(v, 0.f));
        }
    }
    __syncthreads();

    int rt = w >> 1, ct = w & 1;
    f32x4 acc = {0,0,0,0};
#pragma unroll
    for (int kk = 0; kk < 64; kk += 32) {
        s16x8 a = *(const s16x8*)(&T[rt * 16 + l16][kk + q * 8]);
        s16x8 b = *(const s16x8*)(Wg2 + (size_t)(ct * 16 + l16) * 2048 + nb + kk + q * 8);
        acc = __builtin_amdgcn_mfma_f32_16x16x32_bf16(a, b, acc, 0, 0, 0);
    }
    int col = ct * 16 + l16;
#pragma unroll
    for (int rr = 0; rr < 4; rr++)
        atomicAdd(&U[(size_t)(m0 + rt * 16 + q * 4 + rr) * 32 + col], acc[rr]);
}

__global__ __launch_bounds__(256) void gemm_bt32b(
    const float* __restrict__ people, const float* __restrict__ objects,
    const u16* __restrict__ WgT, float* __restrict__ Hp, float* __restrict__ HoF)
{
    int z = blockIdx.z;
    const float* A = z ? objects : people;
    const u16* BT  = z ? WgT + 1024 : WgT;
    float* outF    = z ? HoF : Hp;
    int t = threadIdx.x, lane = t & 63, w = t >> 6;
    int l16 = lane & 15, q = lane >> 4;
    int bm = blockIdx.x * 128 + w * 32;
    int kb = blockIdx.y * 128;
    const float* ap0 = A + (size_t)(bm + l16) * 1024 + kb + q * 8;
    const float* ap1 = A + (size_t)(bm + 16 + l16) * 1024 + kb + q * 8;
    const u16* bp0 = BT + (size_t)l16 * 2048 + kb + q * 8;
    const u16* bp1 = BT + (size_t)(16 + l16) * 2048 + kb + q * 8;
    f32x4 acc00 = {0,0,0,0}, acc01 = {0,0,0,0}, acc10 = {0,0,0,0}, acc11 = {0,0,0,0};
    for (int k = 0; k < 128; k += 32) {
        s16x8 a0 = ld8(ap0); ap0 += 32;
        s16x8 a1 = ld8(ap1); ap1 += 32;
        s16x8 b0 = *(const s16x8*)bp0; bp0 += 32;
        s16x8 b1 = *(const s16x8*)bp1; bp1 += 32;
        acc00 = __builtin_amdgcn_mfma_f32_16x16x32_bf16(a0, b0, acc00, 0, 0, 0);
        acc01 = __builtin_amdgcn_mfma_f32_16x16x32_bf16(a0, b1, acc01, 0, 0, 0);
        acc10 = __builtin_amdgcn_mfma_f32_16x16x32_bf16(a1, b0, acc10, 0, 0, 0);
        acc11 = __builtin_amdgcn_mfma_f32_16x16x32_bf16(a1, b1, acc11, 0, 0, 0);
    }
    f32x4 accs[2][2] = {{acc00, acc01}, {acc10, acc11}};
#pragma unroll
    for (int ii = 0; ii < 2; ii++)
#pragma unroll
        for (int jj = 0; jj < 2; jj++)
#pragma unroll
            for (int r = 0; r < 4; r++)
                atomicAdd(&outF[(size_t)(bm + ii * 16 + q * 4 + r) * 32 + jj * 16 + l16],
                          accs[ii][jj][r]);
}

// ---- mega: per 32-row tile: aho(MFMA) -> p_att -> fref(in-place LDS)+i_ho -> p_ref
// use_bf selects bf16 spatial (fast path) vs fp32 spatial (fallback).
__global__ __launch_bounds__(256) void mega(
    const float* __restrict__ spatial, const u16* __restrict__ spatB, int use_bf,
    const u16* __restrict__ WspatT, const float* __restrict__ bspat,
    const u16* __restrict__ Pp, const u16* __restrict__ Po,
    const u16* __restrict__ Pc, const float* __restrict__ bvis,
    const u16* __restrict__ WrefT, const float* __restrict__ bref,
    const u16* __restrict__ WattT, const float* __restrict__ batt,
    const float* __restrict__ wip, const float* __restrict__ bip,
    float* __restrict__ outI, float* __restrict__ outRef,
    float* __restrict__ outAtt, float* __restrict__ adjw)
{
    __shared__ u16 tile[32][512];
    __shared__ float part[32][8];
    __shared__ float wipS[512];
    int t = threadIdx.x;
    int c0 = blockIdx.x * 32;
    int lane = t & 63, w = t >> 6;
    int l16 = lane & 15, q = lane >> 4;

    {
        float2 u = *(const float2*)(wip + t * 2);
        wipS[t * 2]     = u.x;
        wipS[t * 2 + 1] = u.y;
    }

    // step 1: aho rows c0..c0+31; wave w owns cols [w*128, w*128+128)
    {
        s16x8 a0, a1;
        if (use_bf) {
            a0 = *(const s16x8*)(spatB + (size_t)(c0 + l16) * 32 + q * 8);
            a1 = *(const s16x8*)(spatB + (size_t)(c0 + 16 + l16) * 32 + q * 8);
        } else {
            a0 = ld8(spatial + (size_t)(c0 + l16) * 32 + q * 8);
            a1 = ld8(spatial + (size_t)(c0 + 16 + l16) * 32 + q * 8);
        }
#pragma unroll
        for (int nt = 0; nt < 8; nt++) {
            int n = w * 128 + nt * 16;
            s16x8 b = *(const s16x8*)(WspatT + (size_t)(n + l16) * 32 + q * 8);
            f32x4 acc0 = {0,0,0,0}, acc1 = {0,0,0,0};
            acc0 = __builtin_amdgcn_mfma_f32_16x16x32_bf16(a0, b, acc0, 0, 0, 0);
            acc1 = __builtin_amdgcn_mfma_f32_16x16x32_bf16(a1, b, acc1, 0, 0, 0);
            float bias = bspat[n + l16];
#pragma unroll
            for (int r = 0; r < 4; r++) {
                tile[q * 4 + r][n + l16]      = f2b(fmaxf(acc0[r] + bias, 0.f));
                tile[16 + q * 4 + r][n + l16] = f2b(fmaxf(acc1[r] + bias, 0.f));
            }
        }
    }
    __syncthreads();

    // step 2: p_att = aho @ WattT^T + batt
    {
        int rt = w >> 1, ct = w & 1;
        f32x4 acc = {0,0,0,0};
        for (int k = 0; k < 512; k += 32) {
            s16x8 a = *(const s16x8*)(&tile[rt * 16 + l16][k + q * 8]);
            s16x8 b = *(const s16x8*)(WattT + (size_t)(ct * 16 + l16) * 512 + k + q * 8);
            acc = __builtin_amdgcn_mfma_f32_16x16x32_bf16(a, b, acc, 0, 0, 0);
        }
        int col = ct * 16 + l16;
        if (col < 29) {
            float bias = batt[col];
#pragma unroll
            for (int r = 0; r < 4; r++) {
                int row = c0 + rt * 16 + q * 4 + r;
                outAtt[(size_t)row * 29 + col] = acc[r] + bias;
            }
        }
    }
    __syncthreads();

    // step 3: fref = relu(Pp+Po+Pc+bvis) * aho (in-place); i_ho partials
    {
        int row = t >> 3, g = t & 7;
        int c = c0 + row;
        int rp = c >> 4, bimg = c >> 8;
        int ro = bimg * 16 + (c & 15);
        const u16* ppr = Pp + (size_t)rp * 512;
        const u16* por = Po + (size_t)ro * 512;
        const u16* pcr = Pc + (size_t)bimg * 512;
        float ps = 0.f;
#pragma unroll 4
        for (int j = 0; j < 64; j += 2) {
            int col = g * 64 + j;
            unsigned int upp = *(const unsigned int*)(ppr + col);
            unsigned int upo = *(const unsigned int*)(por + col);
            unsigned int upc = *(const unsigned int*)(pcr + col);
            float2 bv = *(const float2*)(bvis + col);
            unsigned int uah = *(const unsigned int*)(&tile[row][col]);
            float fv0 = fmaxf(b2f((u16)(upp & 0xffff)) + b2f((u16)(upo & 0xffff))
                            + b2f((u16)(upc & 0xffff)) + bv.x, 0.f);
            float fv1 = fmaxf(b2f((u16)(upp >> 16)) + b2f((u16)(upo >> 16))
                            + b2f((u16)(upc >> 16)) + bv.y, 0.f);
            float fr0 = fv0 * b2f((u16)(uah & 0xffff));
            float fr1 = fv1 * b2f((u16)(uah >> 16));
            *(unsigned int*)(&tile[row][col]) =
                (unsigned int)f2b(fr0) | ((unsigned int)f2b(fr1) << 16);
            ps += fr0 * wipS[col] + fr1 * wipS[col + 1];
        }
        part[row][g] = ps;
    }
    __syncthreads();

    if (t < 32) {
        float s = part[t][0] + part[t][1] + part[t][2] + part[t][3]
                + part[t][4] + part[t][5] + part[t][6] + part[t][7] + bip[0];
        outI[c0 + t] = s;
        adjw[c0 + t] = 1.f / (1.f + expf(-s));
    }

    // step 4: p_ref = fref @ WrefT^T + bref
    {
        int rt = w >> 1, ct = w & 1;
        f32x4 acc = {0,0,0,0};
        for (int k = 0; k < 512; k += 32) {
            s16x8 a = *(const s16x8*)(&tile[rt * 16 + l16][k + q * 8]);
            s16x8 b = *(const s16x8*)(WrefT + (size_t)(ct * 16 + l16) * 512 + k + q * 8);
            acc = __builtin_amdgcn_mfma_f32_16x16x32_bf16(a, b, acc, 0, 0, 0);
        }
        int col = ct * 16 + l16;
        if (col < 29) {
            float bias = bref[col];
#pragma unroll
            for (int r = 0; r < 4; r++) {
                int row = c0 + rt * 16 + q * 4 + r;
                outRef[(size_t)row * 29 + col] = acc[r] + bias;
            }
        }
    }
}

// ---- p_graph: per image, tiny adj contractions + broadcast sum -------------
__global__ __launch_bounds__(256) void pgraph2(
    const float* __restrict__ adjw, const float* __restrict__ Hp,
    const float* __restrict__ HoF, const float* __restrict__ Yh,
    const float* __restrict__ Zo, const float* __restrict__ bg,
    float* __restrict__ outG)
{
    int b = blockIdx.x, t = threadIdx.x;
    __shared__ float adjS[16][16];
    __shared__ float YhS[16][32];
    __shared__ float ZoS[15][32];
    __shared__ float PA[16][32];
    __shared__ float OA[16][32];
    adjS[t >> 4][t & 15] = adjw[b * 256 + t];
    for (int i = t; i < 512; i += 256)
        YhS[i >> 5][i & 31] = Yh[(size_t)(b * 16 + (i >> 5)) * 32 + (i & 31)];
    for (int i = t; i < 480; i += 256)
        ZoS[i >> 5][i & 31] = Zo[(size_t)(b * 15 + (i >> 5)) * 32 + (i & 31)];
    __syncthreads();
    for (int i = t; i < 512; i += 256) {
        int p = i >> 5, j = i & 31;
        float s = 0.f;
#pragma unroll
        for (int o = 0; o < 15; o++) s += adjS[p][o + 1] * ZoS[o][j];
        PA[p][j] = s;
        float s2 = 0.f;
#pragma unroll
        for (int pp = 0; pp < 16; pp++) s2 += adjS[pp][p] * YhS[pp][j];
        OA[p][j] = s2;
    }
    __syncthreads();
    int p = t >> 4, l = t & 15;
    const float* hp = Hp + (size_t)(b * 16 + p) * 32;
    const float* ho = HoF + (size_t)(b * 16 + l) * 32;
    size_t c = (size_t)b * 256 + t;
    for (int j = 0; j < 29; j++) {
        float v = hp[j] + ho[j] + bg[j] + PA[p][j];
        if (l >= 1) v += OA[l][j];
        outG[c * 29 + j] = v;
    }
}

extern "C" void kernel_launch(void* const* d_in, const int* in_sizes, int n_in,
                              void* d_out, int out_size, void* d_ws, size_t ws_size,
                              hipStream_t stream)
{
    const float* people  = (const float*)d_in[0];
    const float* objects = (const float*)d_in[1];
    const float* context = (const float*)d_in[2];
    const float* spatial = (const float*)d_in[3];
    const float* Wvis_w  = (const float*)d_in[4];
    const float* Wvis_b  = (const float*)d_in[5];
    const float* Wspat_w = (const float*)d_in[6];
    const float* Wspat_b = (const float*)d_in[7];
    const float* Wip_w   = (const float*)d_in[8];
    const float* Wip_b   = (const float*)d_in[9];
    const float* Wref_w  = (const float*)d_in[10];
    const float* Wref_b  = (const float*)d_in[11];
    const float* Watt_w  = (const float*)d_in[12];
    const float* Watt_b  = (const float*)d_in[13];
    const float* Woh_w   = (const float*)d_in[14];
    const float* Woh_b   = (const float*)d_in[15];
    const float* Who_w   = (const float*)d_in[16];
    const float* Who_b   = (const float*)d_in[17];
    const float* Wg_w    = (const float*)d_in[18];
    const float* Wg_b    = (const float*)d_in[19];

    char* ws = (char*)d_ws;
    u16* WspatT = (u16*)(ws + OFF_WSPATT);
    u16* WrefT  = (u16*)(ws + OFF_WREFT);
    u16* WattT  = (u16*)(ws + OFF_WATTT);
    u16* WgT    = (u16*)(ws + OFF_WGT);
    u16* Ppb    = (u16*)(ws + OFF_PP);
    u16* Pob    = (u16*)(ws + OFF_PO);
    u16* Pcb    = (u16*)(ws + OFF_PC);
    float* adjw = (float*)(ws + OFF_ADJ);
    float* Hp   = (float*)(ws + OFF_HP);
    float* HoF  = (float*)(ws + OFF_HOF);
    float* Yh   = (float*)(ws + OFF_YH);
    float* Zo   = (float*)(ws + OFF_ZO);
    u16* WvisT2 = (u16*)(ws + OFF_WVIST2);
    u16* WhoT2  = (u16*)(ws + OFF_WHOT2);
    u16* WohT2  = (u16*)(ws + OFF_WOHT2);
    u16* peoB   = (u16*)(ws + OFF_PEOB);
    u16* objB   = (u16*)(ws + OFF_OBJB);
    u16* ctxB   = (u16*)(ws + OFF_CTXB);
    u16* spatB  = (u16*)(ws + OFF_SPATB);

    float* outI   = (float*)d_out;        // i_ho   [16384]
    float* outRef = outI + 16384;         // p_ref  [16384,29]
    float* outAtt = outI + 491520;        // p_att  [16384,29]
    float* outG   = outI + 966656;        // p_graph[16384,29]

    const int fast = (ws_size >= WS_FAST_NEED);

    hipMemsetAsync(ws + ZERO_OFF, 0, ZERO_LEN, stream);
    transpose_small<<<256, 256, 0, stream>>>(Wspat_w, Wref_w, Watt_w, Wg_w,
                                             WspatT, WrefT, WattT, WgT);

    if (fast) {
        prep_fast<<<1024, 256, 0, stream>>>(people, objects, context, spatial,
            Wvis_w, Who_w, Woh_w,
            peoB, objB, ctxB, spatB, WvisT2, WhoT2, WohT2);
        gemm3f<<<dim3(8, 33), 256, 0, stream>>>(peoB, objB, ctxB, WvisT2,
                                                Ppb, Pob, Pcb);
        mega<<<512, 256, 0, stream>>>(spatial, spatB, 1, WspatT, Wspat_b,
                                      Ppb, Pob, Pcb, Wvis_b,
                                      WrefT, Wref_b, WattT, Watt_b,
                                      Wip_w, Wip_b,
                                      outI, outRef, outAtt, adjw);
        relu_proj2f<<<dim3(32, 16, 2), 256, 0, stream>>>(peoB, objB,
            WhoT2, Who_b, WohT2, Woh_b, WgT, Yh, Zo);
        gemm_bt32f<<<dim3(8, 8, 2), 256, 0, stream>>>(peoB, objB, WgT, Hp, HoF);
    } else {
        gemm3<<<dim3(8, 33), 256, 0, stream>>>(people, objects, context, Wvis_w,
                                               Ppb, Pob, Pcb);
        mega<<<512, 256, 0, stream>>>(spatial, nullptr, 0, WspatT, Wspat_b,
                                      Ppb, Pob, Pcb, Wvis_b,
                                      WrefT, Wref_b, WattT, Watt_b,
                                      Wip_w, Wip_b,
                                      outI, outRef, outAtt, adjw);
        relu_proj2<<<dim3(32, 16, 2), 256, 0, stream>>>(people, objects,
            Who_w, Who_b, Woh_w, Woh_b, WgT, Yh, Zo);
        gemm_bt32b<<<dim3(8, 8, 2), 256, 0, stream>>>(people, objects, WgT, Hp, HoF);
    }

    pgraph2<<<64, 256, 0, stream>>>(adjw, Hp, HoF, Yh, Zo, Wg_b, outG);
}

// Round 8
// 221.713 us; speedup vs baseline: 1.0689x; 1.0689x over previous
//
#include <hip/hip_runtime.h>

// VSGNet fused pipeline — fp32 in/out, bf16 MFMA compute.
// B=64 P=16 L=16 D=1024 SP=32 PROJ=512 ACT=29, C=16384.
// R7 post-mortem: relu_proj2f stayed 47us with VALUBusy 28%->2% — latency-bound,
// VGPR=32 => zero software pipelining. R8: (1) explicit prefetch (rotating regs)
// in all GEMM k-loops; (2) gemm3f+relu_proj2f+bt32f fused into one 1416-block
// launch; transpose_small merged into prep. ws_size confirmed ~268MB (harness
// poison fill) => fast path only.

typedef unsigned short u16;   // bf16 bits
typedef short s16x8 __attribute__((ext_vector_type(8)));
typedef float f32x4 __attribute__((ext_vector_type(4)));

__device__ __forceinline__ u16 f2b(float f) {
    union { float f; unsigned int i; } v; v.f = f;
    unsigned int r = (v.i + 0x7fffu + ((v.i >> 16) & 1u)) >> 16;  // RNE
    return (u16)r;
}
__device__ __forceinline__ float b2f(u16 u) {
    union { float f; unsigned int i; } v; v.i = ((unsigned int)u) << 16; return v.f;
}
__device__ __forceinline__ s16x8 ld8(const float* p) {
    float4 a = *(const float4*)p;
    float4 b = *(const float4*)(p + 4);
    s16x8 r;
    r[0] = (short)f2b(a.x); r[1] = (short)f2b(a.y);
    r[2] = (short)f2b(a.z); r[3] = (short)f2b(a.w);
    r[4] = (short)f2b(b.x); r[5] = (short)f2b(b.y);
    r[6] = (short)f2b(b.z); r[7] = (short)f2b(b.w);
    return r;
}

// ---------------- workspace layout (bytes) ----------------
#define OFF_WSPATT 0u         // [512][32]  bf16
#define OFF_WREFT  32768u     // [32][512]  bf16 (rows 29..31 zero)
#define OFF_WATTT  65536u     // [32][512]  bf16
#define OFF_WGT    98304u     // [32][2048] bf16
#define OFF_PP     229376u    // [1024][512] bf16
#define OFF_PO     1277952u   // [1024][512] bf16
#define OFF_PC     2326528u   // [64][512]  bf16
#define OFF_ADJ    2392064u   // [16384] f32
#define OFF_HP     2457600u   // [1024][32] f32
#define OFF_HOF    2588672u   // [1024][32] f32
#define OFF_YH     2719744u   // [1024][32] f32
#define OFF_ZO     2850816u   // [960][32]  f32
#define ZERO_OFF   2457600u
#define ZERO_LEN   516096u
#define OFF_WVIST2 2973696u   // [512][3072] bf16 (n-major, k contiguous)
#define OFF_WHOT2  6119424u   // [1024][1024] bf16
#define OFF_WOHT2  8216576u   // [1024][1024] bf16
#define OFF_PEOB   10313728u  // [1024][1024] bf16
#define OFF_OBJB   12410880u  // [1024][1024] bf16
#define OFF_CTXB   14508032u  // [64][1024]  bf16
#define OFF_SPATB  14639104u  // [16384][32] bf16

// ---------------- prep: all bf16 converts + all transposes ------------------
__global__ __launch_bounds__(256) void prep_all(
    const float* __restrict__ people, const float* __restrict__ objects,
    const float* __restrict__ context, const float* __restrict__ spatial,
    const float* __restrict__ Wvis, const float* __restrict__ Who,
    const float* __restrict__ Woh, const float* __restrict__ Wspat,
    const float* __restrict__ Wref, const float* __restrict__ Watt,
    const float* __restrict__ Wg,
    u16* __restrict__ peoB, u16* __restrict__ objB, u16* __restrict__ ctxB,
    u16* __restrict__ spatB, u16* __restrict__ WvisT, u16* __restrict__ WhoT,
    u16* __restrict__ WohT, u16* __restrict__ WspatT, u16* __restrict__ WrefT,
    u16* __restrict__ WattT, u16* __restrict__ WgT)
{
    int g = blockIdx.x * 256 + threadIdx.x;
    int gsz = gridDim.x * 256;
    for (int i = g; i < 1048576; i += gsz) peoB[i] = f2b(people[i]);
    for (int i = g; i < 1048576; i += gsz) objB[i] = f2b(objects[i]);
    for (int i = g; i < 65536; i += gsz)   ctxB[i] = f2b(context[i]);
    for (int i = g; i < 524288; i += gsz)  spatB[i] = f2b(spatial[i]);
    for (int i = g; i < 512 * 3072; i += gsz) {      // WvisT[n][k] <- Wvis[k][n]
        int n = i / 3072, k = i - n * 3072;
        WvisT[i] = f2b(Wvis[(size_t)k * 512 + n]);
    }
    for (int i = g; i < 1048576; i += gsz) {         // WhoT[n][k]
        int n = i >> 10, k = i & 1023;
        WhoT[i] = f2b(Who[(size_t)k * 1024 + n]);
    }
    for (int i = g; i < 1048576; i += gsz) {
        int n = i >> 10, k = i & 1023;
        WohT[i] = f2b(Woh[(size_t)k * 1024 + n]);
    }
    for (int i = g; i < 512 * 32; i += gsz) {
        int n = i >> 5, k = i & 31;
        WspatT[i] = f2b(Wspat[k * 512 + n]);
    }
    for (int i = g; i < 32 * 512; i += gsz) {
        int n = i >> 9, k = i & 511;
        WrefT[i] = (n < 29) ? f2b(Wref[k * 29 + n]) : (u16)0;
        WattT[i] = (n < 29) ? f2b(Watt[k * 29 + n]) : (u16)0;
    }
    for (int i = g; i < 32 * 2048; i += gsz) {
        int n = i >> 11, k = i & 2047;
        WgT[i] = (n < 29) ? f2b(Wg[k * 29 + n]) : (u16)0;
    }
}

// ---------------- fused post-prep GEMMs (flat 1416-block grid) --------------
// [0,264):    Pp/Po/Pc = {peoB,objB,ctxB} @ WvisT
// [264,1288): Yh/Zo split relu-projection (atomicAdd)
// [1288,1416): Hp/HoF split-K (atomicAdd)
// All k-loops software-pipelined (prefetch next fragments before MFMAs).
__global__ __launch_bounds__(256) void fused_gemms(
    const u16* __restrict__ peoB, const u16* __restrict__ objB,
    const u16* __restrict__ ctxB, const u16* __restrict__ WvisT,
    const u16* __restrict__ WhoT, const float* __restrict__ Who_b,
    const u16* __restrict__ WohT, const float* __restrict__ Woh_b,
    const u16* __restrict__ WgT,
    u16* __restrict__ Pp, u16* __restrict__ Po, u16* __restrict__ Pc,
    float* __restrict__ Yh, float* __restrict__ Zo,
    float* __restrict__ Hp, float* __restrict__ HoF)
{
    __shared__ u16 T[32][72];
    int bid = blockIdx.x;
    int t = threadIdx.x;
    int lane = t & 63, w = t >> 6;
    int l16 = lane & 15, q = lane >> 4;
    int wy = w >> 1, wx = w & 1;

    if (bid < 264) {
        // ---------------- gemm3f: 64x64 tile, K=1024 ----------------
        int bx = bid & 7, ty = bid >> 3;
        const u16* A; u16* outB; int koff, bm;
        if (ty < 16)      { A = peoB; outB = Pp; koff = 0;    bm = ty * 64; }
        else if (ty < 32) { A = objB; outB = Po; koff = 1024; bm = (ty - 16) * 64; }
        else              { A = ctxB; outB = Pc; koff = 2048; bm = 0; }
        int bn = bx * 64;

        const u16* ap0 = A + (size_t)(bm + wy * 32 + l16) * 1024 + q * 8;
        const u16* ap1 = ap0 + (size_t)16 * 1024;
        const u16* bp0 = WvisT + (size_t)(bn + wx * 32 + l16) * 3072 + koff + q * 8;
        const u16* bp1 = bp0 + (size_t)16 * 3072;

        f32x4 acc00 = {0,0,0,0}, acc01 = {0,0,0,0}, acc10 = {0,0,0,0}, acc11 = {0,0,0,0};
        s16x8 a0 = *(const s16x8*)ap0, a1 = *(const s16x8*)ap1;
        s16x8 b0 = *(const s16x8*)bp0, b1 = *(const s16x8*)bp1;
#pragma unroll 4
        for (int it = 0; it < 31; it++) {
            ap0 += 32; ap1 += 32; bp0 += 32; bp1 += 32;
            s16x8 a0n = *(const s16x8*)ap0, a1n = *(const s16x8*)ap1;
            s16x8 b0n = *(const s16x8*)bp0, b1n = *(const s16x8*)bp1;
            acc00 = __builtin_amdgcn_mfma_f32_16x16x32_bf16(a0, b0, acc00, 0, 0, 0);
            acc01 = __builtin_amdgcn_mfma_f32_16x16x32_bf16(a0, b1, acc01, 0, 0, 0);
            acc10 = __builtin_amdgcn_mfma_f32_16x16x32_bf16(a1, b0, acc10, 0, 0, 0);
            acc11 = __builtin_amdgcn_mfma_f32_16x16x32_bf16(a1, b1, acc11, 0, 0, 0);
            a0 = a0n; a1 = a1n; b0 = b0n; b1 = b1n;
        }
        acc00 = __builtin_amdgcn_mfma_f32_16x16x32_bf16(a0, b0, acc00, 0, 0, 0);
        acc01 = __builtin_amdgcn_mfma_f32_16x16x32_bf16(a0, b1, acc01, 0, 0, 0);
        acc10 = __builtin_amdgcn_mfma_f32_16x16x32_bf16(a1, b0, acc10, 0, 0, 0);
        acc11 = __builtin_amdgcn_mfma_f32_16x16x32_bf16(a1, b1, acc11, 0, 0, 0);

        f32x4 accs[2][2] = {{acc00, acc01}, {acc10, acc11}};
#pragma unroll
        for (int ii = 0; ii < 2; ii++)
#pragma unroll
            for (int jj = 0; jj < 2; jj++) {
                int col = bn + wx * 32 + jj * 16 + l16;
#pragma unroll
                for (int r = 0; r < 4; r++) {
                    int row = bm + wy * 32 + ii * 16 + q * 4 + r;
                    outB[(size_t)row * 512 + col] = f2b(accs[ii][jj][r]);
                }
            }
    } else if (bid < 1288) {
        // ---------------- relu_proj split: 32 rows x 64-col chunk ----------
        int r3 = bid - 264;
        int bx = r3 & 31, by = (r3 >> 5) & 15, z = r3 >> 9;
        int m0 = bx * 32;
        if (z && m0 >= 960) return;
        const u16* A    = z ? objB : peoB;
        const u16* W1T  = z ? WohT : WhoT;
        const float* bb = z ? Woh_b : Who_b;
        const u16* Wg2  = z ? WgT : WgT + 1024;
        float* U        = z ? Zo : Yh;
        int nb = by * 64;

        int r = m0 + wy * 16 + l16;
        if (z) r = (r / 15) * 16 + (r % 15) + 1;
        const u16* ap = A + (size_t)r * 1024 + q * 8;
        const u16* bp0 = W1T + (size_t)(nb + wx * 32 + l16) * 1024 + q * 8;
        const u16* bp1 = bp0 + (size_t)16 * 1024;

        f32x4 acc0 = {0,0,0,0}, acc1 = {0,0,0,0};
        s16x8 a = *(const s16x8*)ap;
        s16x8 b0 = *(const s16x8*)bp0, b1 = *(const s16x8*)bp1;
#pragma unroll 4
        for (int it = 0; it < 31; it++) {
            ap += 32; bp0 += 32; bp1 += 32;
            s16x8 an = *(const s16x8*)ap;
            s16x8 b0n = *(const s16x8*)bp0, b1n = *(const s16x8*)bp1;
            acc0 = __builtin_amdgcn_mfma_f32_16x16x32_bf16(a, b0, acc0, 0, 0, 0);
            acc1 = __builtin_amdgcn_mfma_f32_16x16x32_bf16(a, b1, acc1, 0, 0, 0);
            a = an; b0 = b0n; b1 = b1n;
        }
        acc0 = __builtin_amdgcn_mfma_f32_16x16x32_bf16(a, b0, acc0, 0, 0, 0);
        acc1 = __builtin_amdgcn_mfma_f32_16x16x32_bf16(a, b1, acc1, 0, 0, 0);

#pragma unroll
        for (int jj = 0; jj < 2; jj++) {
            int col = wx * 32 + jj * 16 + l16;
            float bv = bb[nb + col];
#pragma unroll
            for (int rr = 0; rr < 4; rr++) {
                float v = (jj ? acc1[rr] : acc0[rr]) + bv;
                T[wy * 16 + q * 4 + rr][col] = f2b(fmaxf(v, 0.f));
            }
        }
        __syncthreads();

        int rt = w >> 1, ct = w & 1;
        f32x4 acc = {0,0,0,0};
#pragma unroll
        for (int kk = 0; kk < 64; kk += 32) {
            s16x8 aa = *(const s16x8*)(&T[rt * 16 + l16][kk + q * 8]);
            s16x8 bb2 = *(const s16x8*)(Wg2 + (size_t)(ct * 16 + l16) * 2048 + nb + kk + q * 8);
            acc = __builtin_amdgcn_mfma_f32_16x16x32_bf16(aa, bb2, acc, 0, 0, 0);
        }
        int col = ct * 16 + l16;
#pragma unroll
        for (int rr = 0; rr < 4; rr++)
            atomicAdd(&U[(size_t)(m0 + rt * 16 + q * 4 + rr) * 32 + col], acc[rr]);
    } else {
        // ---------------- bt32 split-K: 128 rows, 128-k chunk ----------------
        int r3 = bid - 1288;
        int bx = r3 & 7, by = (r3 >> 3) & 7, z = r3 >> 6;
        const u16* A  = z ? objB : peoB;
        const u16* BT = z ? WgT + 1024 : WgT;
        float* outF   = z ? HoF : Hp;
        int bm = bx * 128 + w * 32;
        int kb = by * 128;
        const u16* ap0 = A + (size_t)(bm + l16) * 1024 + kb + q * 8;
        const u16* ap1 = A + (size_t)(bm + 16 + l16) * 1024 + kb + q * 8;
        const u16* bp0 = BT + (size_t)l16 * 2048 + kb + q * 8;
        const u16* bp1 = BT + (size_t)(16 + l16) * 2048 + kb + q * 8;
        f32x4 acc00 = {0,0,0,0}, acc01 = {0,0,0,0}, acc10 = {0,0,0,0}, acc11 = {0,0,0,0};
        s16x8 a0 = *(const s16x8*)ap0, a1 = *(const s16x8*)ap1;
        s16x8 b0 = *(const s16x8*)bp0, b1 = *(const s16x8*)bp1;
#pragma unroll
        for (int it = 0; it < 3; it++) {
            ap0 += 32; ap1 += 32; bp0 += 32; bp1 += 32;
            s16x8 a0n = *(const s16x8*)ap0, a1n = *(const s16x8*)ap1;
            s16x8 b0n = *(const s16x8*)bp0, b1n = *(const s16x8*)bp1;
            acc00 = __builtin_amdgcn_mfma_f32_16x16x32_bf16(a0, b0, acc00, 0, 0, 0);
            acc01 = __builtin_amdgcn_mfma_f32_16x16x32_bf16(a0, b1, acc01, 0, 0, 0);
            acc10 = __builtin_amdgcn_mfma_f32_16x16x32_bf16(a1, b0, acc10, 0, 0, 0);
            acc11 = __builtin_amdgcn_mfma_f32_16x16x32_bf16(a1, b1, acc11, 0, 0, 0);
            a0 = a0n; a1 = a1n; b0 = b0n; b1 = b1n;
        }
        acc00 = __builtin_amdgcn_mfma_f32_16x16x32_bf16(a0, b0, acc00, 0, 0, 0);
        acc01 = __builtin_amdgcn_mfma_f32_16x16x32_bf16(a0, b1, acc01, 0, 0, 0);
        acc10 = __builtin_amdgcn_mfma_f32_16x16x32_bf16(a1, b0, acc10, 0, 0, 0);
        acc11 = __builtin_amdgcn_mfma_f32_16x16x32_bf16(a1, b1, acc11, 0, 0, 0);
        f32x4 accs[2][2] = {{acc00, acc01}, {acc10, acc11}};
#pragma unroll
        for (int ii = 0; ii < 2; ii++)
#pragma unroll
            for (int jj = 0; jj < 2; jj++)
#pragma unroll
                for (int r = 0; r < 4; r++)
                    atomicAdd(&outF[(size_t)(bm + ii * 16 + q * 4 + r) * 32 + jj * 16 + l16],
                              accs[ii][jj][r]);
    }
}

// ---- mega: per 32-row tile: aho(MFMA) -> p_att -> fref(in-place LDS)+i_ho -> p_ref
__global__ __launch_bounds__(256) void mega(
    const u16* __restrict__ spatB, const u16* __restrict__ WspatT,
    const float* __restrict__ bspat,
    const u16* __restrict__ Pp, const u16* __restrict__ Po,
    const u16* __restrict__ Pc, const float* __restrict__ bvis,
    const u16* __restrict__ WrefT, const float* __restrict__ bref,
    const u16* __restrict__ WattT, const float* __restrict__ batt,
    const float* __restrict__ wip, const float* __restrict__ bip,
    float* __restrict__ outI, float* __restrict__ outRef,
    float* __restrict__ outAtt, float* __restrict__ adjw)
{
    __shared__ u16 tile[32][512];
    __shared__ float part[32][8];
    __shared__ float wipS[512];
    int t = threadIdx.x;
    int c0 = blockIdx.x * 32;
    int lane = t & 63, w = t >> 6;
    int l16 = lane & 15, q = lane >> 4;

    {
        float2 u = *(const float2*)(wip + t * 2);
        wipS[t * 2]     = u.x;
        wipS[t * 2 + 1] = u.y;
    }

    // step 1: aho rows c0..c0+31; wave w owns cols [w*128, w*128+128)
    {
        s16x8 a0 = *(const s16x8*)(spatB + (size_t)(c0 + l16) * 32 + q * 8);
        s16x8 a1 = *(const s16x8*)(spatB + (size_t)(c0 + 16 + l16) * 32 + q * 8);
#pragma unroll
        for (int nt = 0; nt < 8; nt++) {
            int n = w * 128 + nt * 16;
            s16x8 b = *(const s16x8*)(WspatT + (size_t)(n + l16) * 32 + q * 8);
            f32x4 acc0 = {0,0,0,0}, acc1 = {0,0,0,0};
            acc0 = __builtin_amdgcn_mfma_f32_16x16x32_bf16(a0, b, acc0, 0, 0, 0);
            acc1 = __builtin_amdgcn_mfma_f32_16x16x32_bf16(a1, b, acc1, 0, 0, 0);
            float bias = bspat[n + l16];
#pragma unroll
            for (int r = 0; r < 4; r++) {
                tile[q * 4 + r][n + l16]      = f2b(fmaxf(acc0[r] + bias, 0.f));
                tile[16 + q * 4 + r][n + l16] = f2b(fmaxf(acc1[r] + bias, 0.f));
            }
        }
    }
    __syncthreads();

    // step 2: p_att = aho @ WattT^T + batt
    {
        int rt = w >> 1, ct = w & 1;
        f32x4 acc = {0,0,0,0};
        for (int k = 0; k < 512; k += 32) {
            s16x8 a = *(const s16x8*)(&tile[rt * 16 + l16][k + q * 8]);
            s16x8 b = *(const s16x8*)(WattT + (size_t)(ct * 16 + l16) * 512 + k + q * 8);
            acc = __builtin_amdgcn_mfma_f32_16x16x32_bf16(a, b, acc, 0, 0, 0);
        }
        int col = ct * 16 + l16;
        if (col < 29) {
            float bias = batt[col];
#pragma unroll
            for (int r = 0; r < 4; r++) {
                int row = c0 + rt * 16 + q * 4 + r;
                outAtt[(size_t)row * 29 + col] = acc[r] + bias;
            }
        }
    }
    __syncthreads();

    // step 3: fref = relu(Pp+Po+Pc+bvis) * aho (in-place); i_ho partials
    {
        int row = t >> 3, g = t & 7;
        int c = c0 + row;
        int rp = c >> 4, bimg = c >> 8;
        int ro = bimg * 16 + (c & 15);
        const u16* ppr = Pp + (size_t)rp * 512;
        const u16* por = Po + (size_t)ro * 512;
        const u16* pcr = Pc + (size_t)bimg * 512;
        float ps = 0.f;
#pragma unroll 4
        for (int j = 0; j < 64; j += 2) {
            int col = g * 64 + j;
            unsigned int upp = *(const unsigned int*)(ppr + col);
            unsigned int upo = *(const unsigned int*)(por + col);
            unsigned int upc = *(const unsigned int*)(pcr + col);
            float2 bv = *(const float2*)(bvis + col);
            unsigned int uah = *(const unsigned int*)(&tile[row][col]);
            float fv0 = fmaxf(b2f((u16)(upp & 0xffff)) + b2f((u16)(upo & 0xffff))
                            + b2f((u16)(upc & 0xffff)) + bv.x, 0.f);
            float fv1 = fmaxf(b2f((u16)(upp >> 16)) + b2f((u16)(upo >> 16))
                            + b2f((u16)(upc >> 16)) + bv.y, 0.f);
            float fr0 = fv0 * b2f((u16)(uah & 0xffff));
            float fr1 = fv1 * b2f((u16)(uah >> 16));
            *(unsigned int*)(&tile[row][col]) =
                (unsigned int)f2b(fr0) | ((unsigned int)f2b(fr1) << 16);
            ps += fr0 * wipS[col] + fr1 * wipS[col + 1];
        }
        part[row][g] = ps;
    }
    __syncthreads();

    if (t < 32) {
        float s = part[t][0] + part[t][1] + part[t][2] + part[t][3]
                + part[t][4] + part[t][5] + part[t][6] + part[t][7] + bip[0];
        outI[c0 + t] = s;
        adjw[c0 + t] = 1.f / (1.f + expf(-s));
    }

    // step 4: p_ref = fref @ WrefT^T + bref
    {
        int rt = w >> 1, ct = w & 1;
        f32x4 acc = {0,0,0,0};
        for (int k = 0; k < 512; k += 32) {
            s16x8 a = *(const s16x8*)(&tile[rt * 16 + l16][k + q * 8]);
            s16x8 b = *(const s16x8*)(WrefT + (size_t)(ct * 16 + l16) * 512 + k + q * 8);
            acc = __builtin_amdgcn_mfma_f32_16x16x32_bf16(a, b, acc, 0, 0, 0);
        }
        int col = ct * 16 + l16;
        if (col < 29) {
            float bias = bref[col];
#pragma unroll
            for (int r = 0; r < 4; r++) {
                int row = c0 + rt * 16 + q * 4 + r;
                outRef[(size_t)row * 29 + col] = acc[r] + bias;
            }
        }
    }
}

// ---- p_graph: per image, tiny adj contractions + broadcast sum -------------
__global__ __launch_bounds__(256) void pgraph2(
    const float* __restrict__ adjw, const float* __restrict__ Hp,
    const float* __restrict__ HoF, const float* __restrict__ Yh,
    const float* __restrict__ Zo, const float* __restrict__ bg,
    float* __restrict__ outG)
{
    int b = blockIdx.x, t = threadIdx.x;
    __shared__ float adjS[16][16];
    __shared__ float YhS[16][32];
    __shared__ float ZoS[15][32];
    __shared__ float PA[16][32];
    __shared__ float OA[16][32];
    adjS[t >> 4][t & 15] = adjw[b * 256 + t];
    for (int i = t; i < 512; i += 256)
        YhS[i >> 5][i & 31] = Yh[(size_t)(b * 16 + (i >> 5)) * 32 + (i & 31)];
    for (int i = t; i < 480; i += 256)
        ZoS[i >> 5][i & 31] = Zo[(size_t)(b * 15 + (i >> 5)) * 32 + (i & 31)];
    __syncthreads();
    for (int i = t; i < 512; i += 256) {
        int p = i >> 5, j = i & 31;
        float s = 0.f;
#pragma unroll
        for (int o = 0; o < 15; o++) s += adjS[p][o + 1] * ZoS[o][j];
        PA[p][j] = s;
        float s2 = 0.f;
#pragma unroll
        for (int pp = 0; pp < 16; pp++) s2 += adjS[pp][p] * YhS[pp][j];
        OA[p][j] = s2;
    }
    __syncthreads();
    int p = t >> 4, l = t & 15;
    const float* hp = Hp + (size_t)(b * 16 + p) * 32;
    const float* ho = HoF + (size_t)(b * 16 + l) * 32;
    size_t c = (size_t)b * 256 + t;
    for (int j = 0; j < 29; j++) {
        float v = hp[j] + ho[j] + bg[j] + PA[p][j];
        if (l >= 1) v += OA[l][j];
        outG[c * 29 + j] = v;
    }
}

extern "C" void kernel_launch(void* const* d_in, const int* in_sizes, int n_in,
                              void* d_out, int out_size, void* d_ws, size_t ws_size,
                              hipStream_t stream)
{
    const float* people  = (const float*)d_in[0];
    const float* objects = (const float*)d_in[1];
    const float* context = (const float*)d_in[2];
    const float* spatial = (const float*)d_in[3];
    const float* Wvis_w  = (const float*)d_in[4];
    const float* Wvis_b  = (const float*)d_in[5];
    const float* Wspat_w = (const float*)d_in[6];
    const float* Wspat_b = (const float*)d_in[7];
    const float* Wip_w   = (const float*)d_in[8];
    const float* Wip_b   = (const float*)d_in[9];
    const float* Wref_w  = (const float*)d_in[10];
    const float* Wref_b  = (const float*)d_in[11];
    const float* Watt_w  = (const float*)d_in[12];
    const float* Watt_b  = (const float*)d_in[13];
    const float* Woh_w   = (const float*)d_in[14];
    const float* Woh_b   = (const float*)d_in[15];
    const float* Who_w   = (const float*)d_in[16];
    const float* Who_b   = (const float*)d_in[17];
    const float* Wg_w    = (const float*)d_in[18];
    const float* Wg_b    = (const float*)d_in[19];

    char* ws = (char*)d_ws;
    u16* WspatT = (u16*)(ws + OFF_WSPATT);
    u16* WrefT  = (u16*)(ws + OFF_WREFT);
    u16* WattT  = (u16*)(ws + OFF_WATTT);
    u16* WgT    = (u16*)(ws + OFF_WGT);
    u16* Ppb    = (u16*)(ws + OFF_PP);
    u16* Pob    = (u16*)(ws + OFF_PO);
    u16* Pcb    = (u16*)(ws + OFF_PC);
    float* adjw = (float*)(ws + OFF_ADJ);
    float* Hp   = (float*)(ws + OFF_HP);
    float* HoF  = (float*)(ws + OFF_HOF);
    float* Yh   = (float*)(ws + OFF_YH);
    float* Zo   = (float*)(ws + OFF_ZO);
    u16* WvisT2 = (u16*)(ws + OFF_WVIST2);
    u16* WhoT2  = (u16*)(ws + OFF_WHOT2);
    u16* WohT2  = (u16*)(ws + OFF_WOHT2);
    u16* peoB   = (u16*)(ws + OFF_PEOB);
    u16* objB   = (u16*)(ws + OFF_OBJB);
    u16* ctxB   = (u16*)(ws + OFF_CTXB);
    u16* spatB  = (u16*)(ws + OFF_SPATB);

    float* outI   = (float*)d_out;        // i_ho   [16384]
    float* outRef = outI + 16384;         // p_ref  [16384,29]
    float* outAtt = outI + 491520;        // p_att  [16384,29]
    float* outG   = outI + 966656;        // p_graph[16384,29]

    hipMemsetAsync(ws + ZERO_OFF, 0, ZERO_LEN, stream);

    prep_all<<<1024, 256, 0, stream>>>(people, objects, context, spatial,
        Wvis_w, Who_w, Woh_w, Wspat_w, Wref_w, Watt_w, Wg_w,
        peoB, objB, ctxB, spatB, WvisT2, WhoT2, WohT2,
        WspatT, WrefT, WattT, WgT);

    fused_gemms<<<1416, 256, 0, stream>>>(peoB, objB, ctxB, WvisT2,
        WhoT2, Who_b, WohT2, Woh_b, WgT,
        Ppb, Pob, Pcb, Yh, Zo, Hp, HoF);

    mega<<<512, 256, 0, stream>>>(spatB, WspatT, Wspat_b,
                                  Ppb, Pob, Pcb, Wvis_b,
                                  WrefT, Wref_b, WattT, Watt_b,
                                  Wip_w, Wip_b,
                                  outI, outRef, outAtt, adjw);

    pgraph2<<<64, 256, 0, stream>>>(adjw, Hp, HoF, Yh, Zo, Wg_b, outG);
}

// Round 9
// 188.803 us; speedup vs baseline: 1.2552x; 1.1743x over previous
//
#include <hip/hip_runtime.h>

// VSGNet fused pipeline — fp32 in/out, bf16 MFMA compute.
// B=64 P=16 L=16 D=1024 SP=32 PROJ=512 ACT=29, C=16384.
// R8 post-mortem: fused_gemms 72us, VGPR=56 (depth-1 prefetch), MfmaUtil 3.3%,
// VALUBusy 1.7% — latency-bound, insufficient MLP. R9: depth-2 pipelining in all
// k-loops, relu section retiled to 64x64 (MFMA:load 1.0), prep transposes via
// LDS 64x64 tiles (were 4KB-stride reads ~ 1 elem / 64B line).

typedef unsigned short u16;   // bf16 bits
typedef short s16x8 __attribute__((ext_vector_type(8)));
typedef float f32x4 __attribute__((ext_vector_type(4)));

__device__ __forceinline__ u16 f2b(float f) {
    union { float f; unsigned int i; } v; v.f = f;
    unsigned int r = (v.i + 0x7fffu + ((v.i >> 16) & 1u)) >> 16;  // RNE
    return (u16)r;
}
__device__ __forceinline__ float b2f(u16 u) {
    union { float f; unsigned int i; } v; v.i = ((unsigned int)u) << 16; return v.f;
}
__device__ __forceinline__ unsigned int pack2(float x, float y) {
    return (unsigned int)f2b(x) | ((unsigned int)f2b(y) << 16);
}

// ---------------- workspace layout (bytes) ----------------
#define OFF_WSPATT 0u         // [512][32]  bf16
#define OFF_WREFT  32768u     // [32][512]  bf16 (rows 29..31 zero)
#define OFF_WATTT  65536u     // [32][512]  bf16
#define OFF_WGT    98304u     // [32][2048] bf16
#define OFF_PP     229376u    // [1024][512] bf16
#define OFF_PO     1277952u   // [1024][512] bf16
#define OFF_PC     2326528u   // [64][512]  bf16
#define OFF_ADJ    2392064u   // [16384] f32
#define OFF_HP     2457600u   // [1024][32] f32
#define OFF_HOF    2588672u   // [1024][32] f32
#define OFF_YH     2719744u   // [1024][32] f32
#define OFF_ZO     2850816u   // [960][32]  f32
#define ZERO_OFF   2457600u
#define ZERO_LEN   516096u
#define OFF_WVIST2 2973696u   // [512][3072] bf16 (n-major, k contiguous)
#define OFF_WHOT2  6119424u   // [1024][1024] bf16
#define OFF_WOHT2  8216576u   // [1024][1024] bf16
#define OFF_PEOB   10313728u  // [1024][1024] bf16
#define OFF_OBJB   12410880u  // [1024][1024] bf16
#define OFF_CTXB   14508032u  // [64][1024]  bf16
#define OFF_SPATB  14639104u  // [16384][32] bf16

// ---------------- prep: LDS-tiled big transposes + vectorized converts ------
// bids [0,896): 64x64 transpose tiles (Who:256, Woh:256, Wvis:384)
// bids [896,1408): grid-stride converts + small head transposes
__global__ __launch_bounds__(256) void prep_all(
    const float* __restrict__ people, const float* __restrict__ objects,
    const float* __restrict__ context, const float* __restrict__ spatial,
    const float* __restrict__ Wvis, const float* __restrict__ Who,
    const float* __restrict__ Woh, const float* __restrict__ Wspat,
    const float* __restrict__ Wref, const float* __restrict__ Watt,
    const float* __restrict__ Wg,
    u16* __restrict__ peoB, u16* __restrict__ objB, u16* __restrict__ ctxB,
    u16* __restrict__ spatB, u16* __restrict__ WvisT, u16* __restrict__ WhoT,
    u16* __restrict__ WohT, u16* __restrict__ WspatT, u16* __restrict__ WrefT,
    u16* __restrict__ WattT, u16* __restrict__ WgT)
{
    __shared__ float S[64][65];
    int bid = blockIdx.x, t = threadIdx.x;
    if (bid < 896) {
        const float* src; u16* dst; int N, K, kt, nt;
        int tb = bid;
        if (tb < 256)      { src = Who;  dst = WhoT;  K = 1024; N = 1024; kt = tb >> 4; nt = tb & 15; }
        else if (tb < 512) { tb -= 256; src = Woh;  dst = WohT;  K = 1024; N = 1024; kt = tb >> 4; nt = tb & 15; }
        else               { tb -= 512; src = Wvis; dst = WvisT; K = 3072; N = 512;  kt = tb >> 3; nt = tb & 7; }
        int k0 = kt * 64, n0 = nt * 64;
        int tx = t & 63, ty = t >> 6;   // 4 rows/pass
#pragma unroll
        for (int i = 0; i < 16; i++)
            S[ty + 4 * i][tx] = src[(size_t)(k0 + ty + 4 * i) * N + n0 + tx];
        __syncthreads();
#pragma unroll
        for (int i = 0; i < 16; i++)
            dst[(size_t)(n0 + ty + 4 * i) * K + k0 + tx] = f2b(S[tx][ty + 4 * i]);
        return;
    }
    int g = (bid - 896) * 256 + t;
    const int gsz = 512 * 256;
    for (int i = g; i < 524288; i += gsz) {   // people (1M elems as float2)
        float2 v = ((const float2*)people)[i];
        ((unsigned int*)peoB)[i] = pack2(v.x, v.y);
    }
    for (int i = g; i < 524288; i += gsz) {   // objects
        float2 v = ((const float2*)objects)[i];
        ((unsigned int*)objB)[i] = pack2(v.x, v.y);
    }
    for (int i = g; i < 32768; i += gsz) {    // context
        float2 v = ((const float2*)context)[i];
        ((unsigned int*)ctxB)[i] = pack2(v.x, v.y);
    }
    for (int i = g; i < 262144; i += gsz) {   // spatial
        float2 v = ((const float2*)spatial)[i];
        ((unsigned int*)spatB)[i] = pack2(v.x, v.y);
    }
    for (int i = g; i < 512 * 32; i += gsz) {
        int n = i >> 5, k = i & 31;
        WspatT[i] = f2b(Wspat[k * 512 + n]);
    }
    for (int i = g; i < 32 * 512; i += gsz) {
        int n = i >> 9, k = i & 511;
        WrefT[i] = (n < 29) ? f2b(Wref[k * 29 + n]) : (u16)0;
        WattT[i] = (n < 29) ? f2b(Watt[k * 29 + n]) : (u16)0;
    }
    for (int i = g; i < 32 * 2048; i += gsz) {
        int n = i >> 11, k = i & 2047;
        WgT[i] = (n < 29) ? f2b(Wg[k * 29 + n]) : (u16)0;
    }
}

// ---------------- fused post-prep GEMMs (flat 888-block grid) ---------------
// [0,264):   Pp/Po/Pc = {peoB,objB,ctxB} @ WvisT  (64x64, depth-2 pipeline)
// [264,760): Yh/Zo relu-projection, 64x64 tiles (atomicAdd)
// [760,888): Hp/HoF split-K (atomicAdd)
__global__ __launch_bounds__(256) void fused_gemms(
    const u16* __restrict__ peoB, const u16* __restrict__ objB,
    const u16* __restrict__ ctxB, const u16* __restrict__ WvisT,
    const u16* __restrict__ WhoT, const float* __restrict__ Who_b,
    const u16* __restrict__ WohT, const float* __restrict__ Woh_b,
    const u16* __restrict__ WgT,
    u16* __restrict__ Pp, u16* __restrict__ Po, u16* __restrict__ Pc,
    float* __restrict__ Yh, float* __restrict__ Zo,
    float* __restrict__ Hp, float* __restrict__ HoF)
{
    __shared__ u16 T[64][72];
    int bid = blockIdx.x;
    int t = threadIdx.x;
    int lane = t & 63, w = t >> 6;
    int l16 = lane & 15, q = lane >> 4;
    int wy = w >> 1, wx = w & 1;

    if (bid < 264) {
        // ---------------- gemm3: 64x64 tile, K=1024 ----------------
        int bx = bid & 7, ty = bid >> 3;
        const u16* A; u16* outB; int koff, bm;
        if (ty < 16)      { A = peoB; outB = Pp; koff = 0;    bm = ty * 64; }
        else if (ty < 32) { A = objB; outB = Po; koff = 1024; bm = (ty - 16) * 64; }
        else              { A = ctxB; outB = Pc; koff = 2048; bm = 0; }
        int bn = bx * 64;

        const u16* ap0 = A + (size_t)(bm + wy * 32 + l16) * 1024 + q * 8;
        const u16* ap1 = ap0 + (size_t)16 * 1024;
        const u16* bp0 = WvisT + (size_t)(bn + wx * 32 + l16) * 3072 + koff + q * 8;
        const u16* bp1 = bp0 + (size_t)16 * 3072;

        f32x4 acc00 = {0,0,0,0}, acc01 = {0,0,0,0}, acc10 = {0,0,0,0}, acc11 = {0,0,0,0};
        s16x8 ca0 = *(const s16x8*)ap0,        ca1 = *(const s16x8*)ap1;
        s16x8 cb0 = *(const s16x8*)bp0,        cb1 = *(const s16x8*)bp1;
        s16x8 na0 = *(const s16x8*)(ap0 + 32), na1 = *(const s16x8*)(ap1 + 32);
        s16x8 nb0 = *(const s16x8*)(bp0 + 32), nb1 = *(const s16x8*)(bp1 + 32);
        ap0 += 64; ap1 += 64; bp0 += 64; bp1 += 64;
        for (int it = 0; it < 30; it++) {
            s16x8 ta0 = *(const s16x8*)ap0, ta1 = *(const s16x8*)ap1;
            s16x8 tb0 = *(const s16x8*)bp0, tb1 = *(const s16x8*)bp1;
            ap0 += 32; ap1 += 32; bp0 += 32; bp1 += 32;
            acc00 = __builtin_amdgcn_mfma_f32_16x16x32_bf16(ca0, cb0, acc00, 0, 0, 0);
            acc01 = __builtin_amdgcn_mfma_f32_16x16x32_bf16(ca0, cb1, acc01, 0, 0, 0);
            acc10 = __builtin_amdgcn_mfma_f32_16x16x32_bf16(ca1, cb0, acc10, 0, 0, 0);
            acc11 = __builtin_amdgcn_mfma_f32_16x16x32_bf16(ca1, cb1, acc11, 0, 0, 0);
            ca0 = na0; ca1 = na1; cb0 = nb0; cb1 = nb1;
            na0 = ta0; na1 = ta1; nb0 = tb0; nb1 = tb1;
        }
        acc00 = __builtin_amdgcn_mfma_f32_16x16x32_bf16(ca0, cb0, acc00, 0, 0, 0);
        acc01 = __builtin_amdgcn_mfma_f32_16x16x32_bf16(ca0, cb1, acc01, 0, 0, 0);
        acc10 = __builtin_amdgcn_mfma_f32_16x16x32_bf16(ca1, cb0, acc10, 0, 0, 0);
        acc11 = __builtin_amdgcn_mfma_f32_16x16x32_bf16(ca1, cb1, acc11, 0, 0, 0);
        acc00 = __builtin_amdgcn_mfma_f32_16x16x32_bf16(na0, nb0, acc00, 0, 0, 0);
        acc01 = __builtin_amdgcn_mfma_f32_16x16x32_bf16(na0, nb1, acc01, 0, 0, 0);
        acc10 = __builtin_amdgcn_mfma_f32_16x16x32_bf16(na1, nb0, acc10, 0, 0, 0);
        acc11 = __builtin_amdgcn_mfma_f32_16x16x32_bf16(na1, nb1, acc11, 0, 0, 0);

        f32x4 accs[2][2] = {{acc00, acc01}, {acc10, acc11}};
#pragma unroll
        for (int ii = 0; ii < 2; ii++)
#pragma unroll
            for (int jj = 0; jj < 2; jj++) {
                int col = bn + wx * 32 + jj * 16 + l16;
#pragma unroll
                for (int r = 0; r < 4; r++) {
                    int row = bm + wy * 32 + ii * 16 + q * 4 + r;
                    outB[(size_t)row * 512 + col] = f2b(accs[ii][jj][r]);
                }
            }
    } else if (bid < 760) {
        // ---------------- relu-projection: 64 rows x 64-col chunk ----------
        int r3 = bid - 264;
        int z, rt, nbt;
        if (r3 < 256) { z = 0; rt = r3 >> 4; nbt = r3 & 15; }
        else          { z = 1; r3 -= 256; rt = r3 >> 4; nbt = r3 & 15; }
        const u16* A    = z ? objB : peoB;
        const u16* W1T  = z ? WohT : WhoT;
        const float* bb = z ? Woh_b : Who_b;
        const u16* Wg2  = z ? WgT : WgT + 1024;
        float* U        = z ? Zo : Yh;
        int m0 = rt * 64, nb = nbt * 64;

        int r0 = m0 + wy * 32 + l16;
        int r1 = r0 + 16;
        if (z) { r0 = (r0 / 15) * 16 + (r0 % 15) + 1;
                 r1 = (r1 / 15) * 16 + (r1 % 15) + 1; }
        const u16* ap0 = A + (size_t)r0 * 1024 + q * 8;
        const u16* ap1 = A + (size_t)r1 * 1024 + q * 8;
        const u16* bp0 = W1T + (size_t)(nb + wx * 32 + l16) * 1024 + q * 8;
        const u16* bp1 = bp0 + (size_t)16 * 1024;

        f32x4 acc00 = {0,0,0,0}, acc01 = {0,0,0,0}, acc10 = {0,0,0,0}, acc11 = {0,0,0,0};
        s16x8 ca0 = *(const s16x8*)ap0,        ca1 = *(const s16x8*)ap1;
        s16x8 cb0 = *(const s16x8*)bp0,        cb1 = *(const s16x8*)bp1;
        s16x8 na0 = *(const s16x8*)(ap0 + 32), na1 = *(const s16x8*)(ap1 + 32);
        s16x8 nb0 = *(const s16x8*)(bp0 + 32), nb1 = *(const s16x8*)(bp1 + 32);
        ap0 += 64; ap1 += 64; bp0 += 64; bp1 += 64;
        for (int it = 0; it < 30; it++) {
            s16x8 ta0 = *(const s16x8*)ap0, ta1 = *(const s16x8*)ap1;
            s16x8 tb0 = *(const s16x8*)bp0, tb1 = *(const s16x8*)bp1;
            ap0 += 32; ap1 += 32; bp0 += 32; bp1 += 32;
            acc00 = __builtin_amdgcn_mfma_f32_16x16x32_bf16(ca0, cb0, acc00, 0, 0, 0);
            acc01 = __builtin_amdgcn_mfma_f32_16x16x32_bf16(ca0, cb1, acc01, 0, 0, 0);
            acc10 = __builtin_amdgcn_mfma_f32_16x16x32_bf16(ca1, cb0, acc10, 0, 0, 0);
            acc11 = __builtin_amdgcn_mfma_f32_16x16x32_bf16(ca1, cb1, acc11, 0, 0, 0);
            ca0 = na0; ca1 = na1; cb0 = nb0; cb1 = nb1;
            na0 = ta0; na1 = ta1; nb0 = tb0; nb1 = tb1;
        }
        acc00 = __builtin_amdgcn_mfma_f32_16x16x32_bf16(ca0, cb0, acc00, 0, 0, 0);
        acc01 = __builtin_amdgcn_mfma_f32_16x16x32_bf16(ca0, cb1, acc01, 0, 0, 0);
        acc10 = __builtin_amdgcn_mfma_f32_16x16x32_bf16(ca1, cb0, acc10, 0, 0, 0);
        acc11 = __builtin_amdgcn_mfma_f32_16x16x32_bf16(ca1, cb1, acc11, 0, 0, 0);
        acc00 = __builtin_amdgcn_mfma_f32_16x16x32_bf16(na0, nb0, acc00, 0, 0, 0);
        acc01 = __builtin_amdgcn_mfma_f32_16x16x32_bf16(na0, nb1, acc01, 0, 0, 0);
        acc10 = __builtin_amdgcn_mfma_f32_16x16x32_bf16(na1, nb0, acc10, 0, 0, 0);
        acc11 = __builtin_amdgcn_mfma_f32_16x16x32_bf16(na1, nb1, acc11, 0, 0, 0);

        // bias + relu -> T (cols partitioned across nb-blocks: bias added once)
        f32x4 accs[2][2] = {{acc00, acc01}, {acc10, acc11}};
#pragma unroll
        for (int ii = 0; ii < 2; ii++)
#pragma unroll
            for (int jj = 0; jj < 2; jj++) {
                int col = wx * 32 + jj * 16 + l16;
                float bv = bb[nb + col];
#pragma unroll
                for (int rr = 0; rr < 4; rr++) {
                    float v = accs[ii][jj][rr] + bv;
                    T[wy * 32 + ii * 16 + q * 4 + rr][col] = f2b(fmaxf(v, 0.f));
                }
            }
        __syncthreads();

        // stage 2: U_part[64x32] = T(64x64) @ Wg2[nb:nb+64, :32]; wave strip 16 rows
        f32x4 s20 = {0,0,0,0}, s21 = {0,0,0,0};
#pragma unroll
        for (int kk = 0; kk < 64; kk += 32) {
            s16x8 a2 = *(const s16x8*)(&T[w * 16 + l16][kk + q * 8]);
            s16x8 b20 = *(const s16x8*)(Wg2 + (size_t)l16 * 2048 + nb + kk + q * 8);
            s16x8 b21 = *(const s16x8*)(Wg2 + (size_t)(16 + l16) * 2048 + nb + kk + q * 8);
            s20 = __builtin_amdgcn_mfma_f32_16x16x32_bf16(a2, b20, s20, 0, 0, 0);
            s21 = __builtin_amdgcn_mfma_f32_16x16x32_bf16(a2, b21, s21, 0, 0, 0);
        }
#pragma unroll
        for (int rr = 0; rr < 4; rr++) {
            int row = m0 + w * 16 + q * 4 + rr;
            atomicAdd(&U[(size_t)row * 32 + l16], s20[rr]);
            atomicAdd(&U[(size_t)row * 32 + 16 + l16], s21[rr]);
        }
    } else {
        // ---------------- bt32 split-K: 128 rows, 128-k chunk ----------------
        int r3 = bid - 760;
        int bx = r3 & 7, by = (r3 >> 3) & 7, z = r3 >> 6;
        const u16* A  = z ? objB : peoB;
        const u16* BT = z ? WgT + 1024 : WgT;
        float* outF   = z ? HoF : Hp;
        int bm = bx * 128 + w * 32;
        int kb = by * 128;
        const u16* ap0 = A + (size_t)(bm + l16) * 1024 + kb + q * 8;
        const u16* ap1 = A + (size_t)(bm + 16 + l16) * 1024 + kb + q * 8;
        const u16* bp0 = BT + (size_t)l16 * 2048 + kb + q * 8;
        const u16* bp1 = BT + (size_t)(16 + l16) * 2048 + kb + q * 8;
        f32x4 acc00 = {0,0,0,0}, acc01 = {0,0,0,0}, acc10 = {0,0,0,0}, acc11 = {0,0,0,0};
        s16x8 ca0 = *(const s16x8*)ap0,        ca1 = *(const s16x8*)ap1;
        s16x8 cb0 = *(const s16x8*)bp0,        cb1 = *(const s16x8*)bp1;
        s16x8 na0 = *(const s16x8*)(ap0 + 32), na1 = *(const s16x8*)(ap1 + 32);
        s16x8 nb0 = *(const s16x8*)(bp0 + 32), nb1 = *(const s16x8*)(bp1 + 32);
        ap0 += 64; ap1 += 64; bp0 += 64; bp1 += 64;
#pragma unroll
        for (int it = 0; it < 2; it++) {
            s16x8 ta0 = *(const s16x8*)ap0, ta1 = *(const s16x8*)ap1;
            s16x8 tb0 = *(const s16x8*)bp0, tb1 = *(const s16x8*)bp1;
            ap0 += 32; ap1 += 32; bp0 += 32; bp1 += 32;
            acc00 = __builtin_amdgcn_mfma_f32_16x16x32_bf16(ca0, cb0, acc00, 0, 0, 0);
            acc01 = __builtin_amdgcn_mfma_f32_16x16x32_bf16(ca0, cb1, acc01, 0, 0, 0);
            acc10 = __builtin_amdgcn_mfma_f32_16x16x32_bf16(ca1, cb0, acc10, 0, 0, 0);
            acc11 = __builtin_amdgcn_mfma_f32_16x16x32_bf16(ca1, cb1, acc11, 0, 0, 0);
            ca0 = na0; ca1 = na1; cb0 = nb0; cb1 = nb1;
            na0 = ta0; na1 = ta1; nb0 = tb0; nb1 = tb1;
        }
        acc00 = __builtin_amdgcn_mfma_f32_16x16x32_bf16(ca0, cb0, acc00, 0, 0, 0);
        acc01 = __builtin_amdgcn_mfma_f32_16x16x32_bf16(ca0, cb1, acc01, 0, 0, 0);
        acc10 = __builtin_amdgcn_mfma_f32_16x16x32_bf16(ca1, cb0, acc10, 0, 0, 0);
        acc11 = __builtin_amdgcn_mfma_f32_16x16x32_bf16(ca1, cb1, acc11, 0, 0, 0);
        acc00 = __builtin_amdgcn_mfma_f32_16x16x32_bf16(na0, nb0, acc00, 0, 0, 0);
        acc01 = __builtin_amdgcn_mfma_f32_16x16x32_bf16(na0, nb1, acc01, 0, 0, 0);
        acc10 = __builtin_amdgcn_mfma_f32_16x16x32_bf16(na1, nb0, acc10, 0, 0, 0);
        acc11 = __builtin_amdgcn_mfma_f32_16x16x32_bf16(na1, nb1, acc11, 0, 0, 0);
        f32x4 accs[2][2] = {{acc00, acc01}, {acc10, acc11}};
#pragma unroll
        for (int ii = 0; ii < 2; ii++)
#pragma unroll
            for (int jj = 0; jj < 2; jj++)
#pragma unroll
                for (int r = 0; r < 4; r++)
                    atomicAdd(&outF[(size_t)(bm + ii * 16 + q * 4 + r) * 32 + jj * 16 + l16],
                              accs[ii][jj][r]);
    }
}

// ---- mega: per 32-row tile: aho(MFMA) -> p_att -> fref(in-place LDS)+i_ho -> p_ref
__global__ __launch_bounds__(256) void mega(
    const u16* __restrict__ spatB, const u16* __restrict__ WspatT,
    const float* __restrict__ bspat,
    const u16* __restrict__ Pp, const u16* __restrict__ Po,
    const u16* __restrict__ Pc, const float* __restrict__ bvis,
    const u16* __restrict__ WrefT, const float* __restrict__ bref,
    const u16* __restrict__ WattT, const float* __restrict__ batt,
    const float* __restrict__ wip, const float* __restrict__ bip,
    float* __restrict__ outI, float* __restrict__ outRef,
    float* __restrict__ outAtt, float* __restrict__ adjw)
{
    __shared__ u16 tile[32][512];
    __shared__ float part[32][8];
    __shared__ float wipS[512];
    int t = threadIdx.x;
    int c0 = blockIdx.x * 32;
    int lane = t & 63, w = t >> 6;
    int l16 = lane & 15, q = lane >> 4;

    {
        float2 u = *(const float2*)(wip + t * 2);
        wipS[t * 2]     = u.x;
        wipS[t * 2 + 1] = u.y;
    }

    // step 1: aho rows c0..c0+31; wave w owns cols [w*128, w*128+128)
    {
        s16x8 a0 = *(const s16x8*)(spatB + (size_t)(c0 + l16) * 32 + q * 8);
        s16x8 a1 = *(const s16x8*)(spatB + (size_t)(c0 + 16 + l16) * 32 + q * 8);
        const u16* wb = WspatT + (size_t)(w * 128 + l16) * 32 + q * 8;
        s16x8 cb = *(const s16x8*)wb;
        s16x8 nb_ = *(const s16x8*)(wb + 16 * 32);
        wb += 32 * 32;
#pragma unroll
        for (int nt = 0; nt < 8; nt++) {
            s16x8 tb;
            if (nt < 6) { tb = *(const s16x8*)wb; wb += 16 * 32; }
            int n = w * 128 + nt * 16;
            f32x4 acc0 = {0,0,0,0}, acc1 = {0,0,0,0};
            acc0 = __builtin_amdgcn_mfma_f32_16x16x32_bf16(a0, cb, acc0, 0, 0, 0);
            acc1 = __builtin_amdgcn_mfma_f32_16x16x32_bf16(a1, cb, acc1, 0, 0, 0);
            cb = nb_; nb_ = tb;
            float bias = bspat[n + l16];
#pragma unroll
            for (int r = 0; r < 4; r++) {
                tile[q * 4 + r][n + l16]      = f2b(fmaxf(acc0[r] + bias, 0.f));
                tile[16 + q * 4 + r][n + l16] = f2b(fmaxf(acc1[r] + bias, 0.f));
            }
        }
    }
    __syncthreads();

    // step 2: p_att = aho @ WattT^T + batt  (depth-2 on W loads)
    {
        int rt = w >> 1, ct = w & 1;
        const u16* bp = WattT + (size_t)(ct * 16 + l16) * 512 + q * 8;
        f32x4 acc = {0,0,0,0};
        s16x8 cb = *(const s16x8*)bp;
        s16x8 nb_ = *(const s16x8*)(bp + 32);
        bp += 64;
        for (int i = 0; i < 14; i++) {
            s16x8 tb = *(const s16x8*)bp; bp += 32;
            s16x8 a = *(const s16x8*)(&tile[rt * 16 + l16][i * 32 + q * 8]);
            acc = __builtin_amdgcn_mfma_f32_16x16x32_bf16(a, cb, acc, 0, 0, 0);
            cb = nb_; nb_ = tb;
        }
        {
            s16x8 a = *(const s16x8*)(&tile[rt * 16 + l16][14 * 32 + q * 8]);
            acc = __builtin_amdgcn_mfma_f32_16x16x32_bf16(a, cb, acc, 0, 0, 0);
            a = *(const s16x8*)(&tile[rt * 16 + l16][15 * 32 + q * 8]);
            acc = __builtin_amdgcn_mfma_f32_16x16x32_bf16(a, nb_, acc, 0, 0, 0);
        }
        int col = ct * 16 + l16;
        if (col < 29) {
            float bias = batt[col];
#pragma unroll
            for (int r = 0; r < 4; r++) {
                int row = c0 + rt * 16 + q * 4 + r;
                outAtt[(size_t)row * 29 + col] = acc[r] + bias;
            }
        }
    }
    __syncthreads();

    // step 3: fref = relu(Pp+Po+Pc+bvis) * aho (in-place); i_ho partials
    {
        int row = t >> 3, g = t & 7;
        int c = c0 + row;
        int rp = c >> 4, bimg = c >> 8;
        int ro = bimg * 16 + (c & 15);
        const u16* ppr = Pp + (size_t)rp * 512;
        const u16* por = Po + (size_t)ro * 512;
        const u16* pcr = Pc + (size_t)bimg * 512;
        float ps = 0.f;
#pragma unroll 4
        for (int j = 0; j < 64; j += 2) {
            int col = g * 64 + j;
            unsigned int upp = *(const unsigned int*)(ppr + col);
            unsigned int upo = *(const unsigned int*)(por + col);
            unsigned int upc = *(const unsigned int*)(pcr + col);
            float2 bv = *(const float2*)(bvis + col);
            unsigned int uah = *(const unsigned int*)(&tile[row][col]);
            float fv0 = fmaxf(b2f((u16)(upp & 0xffff)) + b2f((u16)(upo & 0xffff))
                            + b2f((u16)(upc & 0xffff)) + bv.x, 0.f);
            float fv1 = fmaxf(b2f((u16)(upp >> 16)) + b2f((u16)(upo >> 16))
                            + b2f((u16)(upc >> 16)) + bv.y, 0.f);
            float fr0 = fv0 * b2f((u16)(uah & 0xffff));
            float fr1 = fv1 * b2f((u16)(uah >> 16));
            *(unsigned int*)(&tile[row][col]) = pack2(fr0, fr1);
            ps += fr0 * wipS[col] + fr1 * wipS[col + 1];
        }
        part[row][g] = ps;
    }
    __syncthreads();

    if (t < 32) {
        float s = part[t][0] + part[t][1] + part[t][2] + part[t][3]
                + part[t][4] + part[t][5] + part[t][6] + part[t][7] + bip[0];
        outI[c0 + t] = s;
        adjw[c0 + t] = 1.f / (1.f + expf(-s));
    }

    // step 4: p_ref = fref @ WrefT^T + bref  (depth-2 on W loads)
    {
        int rt = w >> 1, ct = w & 1;
        const u16* bp = WrefT + (size_t)(ct * 16 + l16) * 512 + q * 8;
        f32x4 acc = {0,0,0,0};
        s16x8 cb = *(const s16x8*)bp;
        s16x8 nb_ = *(const s16x8*)(bp + 32);
        bp += 64;
        for (int i = 0; i < 14; i++) {
            s16x8 tb = *(const s16x8*)bp; bp += 32;
            s16x8 a = *(const s16x8*)(&tile[rt * 16 + l16][i * 32 + q * 8]);
            acc = __builtin_amdgcn_mfma_f32_16x16x32_bf16(a, cb, acc, 0, 0, 0);
            cb = nb_; nb_ = tb;
        }
        {
            s16x8 a = *(const s16x8*)(&tile[rt * 16 + l16][14 * 32 + q * 8]);
            acc = __builtin_amdgcn_mfma_f32_16x16x32_bf16(a, cb, acc, 0, 0, 0);
            a = *(const s16x8*)(&tile[rt * 16 + l16][15 * 32 + q * 8]);
            acc = __builtin_amdgcn_mfma_f32_16x16x32_bf16(a, nb_, acc, 0, 0, 0);
        }
        int col = ct * 16 + l16;
        if (col < 29) {
            float bias = bref[col];
#pragma unroll
            for (int r = 0; r < 4; r++) {
                int row = c0 + rt * 16 + q * 4 + r;
                outRef[(size_t)row * 29 + col] = acc[r] + bias;
            }
        }
    }
}

// ---- p_graph: per image, tiny adj contractions + broadcast sum -------------
__global__ __launch_bounds__(256) void pgraph2(
    const float* __restrict__ adjw, const float* __restrict__ Hp,
    const float* __restrict__ HoF, const float* __restrict__ Yh,
    const float* __restrict__ Zo, const float* __restrict__ bg,
    float* __restrict__ outG)
{
    int b = blockIdx.x, t = threadIdx.x;
    __shared__ float adjS[16][16];
    __shared__ float YhS[16][32];
    __shared__ float ZoS[15][32];
    __shared__ float PA[16][32];
    __shared__ float OA[16][32];
    adjS[t >> 4][t & 15] = adjw[b * 256 + t];
    for (int i = t; i < 512; i += 256)
        YhS[i >> 5][i & 31] = Yh[(size_t)(b * 16 + (i >> 5)) * 32 + (i & 31)];
    for (int i = t; i < 480; i += 256)
        ZoS[i >> 5][i & 31] = Zo[(size_t)(b * 15 + (i >> 5)) * 32 + (i & 31)];
    __syncthreads();
    for (int i = t; i < 512; i += 256) {
        int p = i >> 5, j = i & 31;
        float s = 0.f;
#pragma unroll
        for (int o = 0; o < 15; o++) s += adjS[p][o + 1] * ZoS[o][j];
        PA[p][j] = s;
        float s2 = 0.f;
#pragma unroll
        for (int pp = 0; pp < 16; pp++) s2 += adjS[pp][p] * YhS[pp][j];
        OA[p][j] = s2;
    }
    __syncthreads();
    int p = t >> 4, l = t & 15;
    const float* hp = Hp + (size_t)(b * 16 + p) * 32;
    const float* ho = HoF + (size_t)(b * 16 + l) * 32;
    size_t c = (size_t)b * 256 + t;
    for (int j = 0; j < 29; j++) {
        float v = hp[j] + ho[j] + bg[j] + PA[p][j];
        if (l >= 1) v += OA[l][j];
        outG[c * 29 + j] = v;
    }
}

extern "C" void kernel_launch(void* const* d_in, const int* in_sizes, int n_in,
                              void* d_out, int out_size, void* d_ws, size_t ws_size,
                              hipStream_t stream)
{
    const float* people  = (const float*)d_in[0];
    const float* objects = (const float*)d_in[1];
    const float* context = (const float*)d_in[2];
    const float* spatial = (const float*)d_in[3];
    const float* Wvis_w  = (const float*)d_in[4];
    const float* Wvis_b  = (const float*)d_in[5];
    const float* Wspat_w = (const float*)d_in[6];
    const float* Wspat_b = (const float*)d_in[7];
    const float* Wip_w   = (const float*)d_in[8];
    const float* Wip_b   = (const float*)d_in[9];
    const float* Wref_w  = (const float*)d_in[10];
    const float* Wref_b  = (const float*)d_in[11];
    const float* Watt_w  = (const float*)d_in[12];
    const float* Watt_b  = (const float*)d_in[13];
    const float* Woh_w   = (const float*)d_in[14];
    const float* Woh_b   = (const float*)d_in[15];
    const float* Who_w   = (const float*)d_in[16];
    const float* Who_b   = (const float*)d_in[17];
    const float* Wg_w    = (const float*)d_in[18];
    const float* Wg_b    = (const float*)d_in[19];

    char* ws = (char*)d_ws;
    u16* WspatT = (u16*)(ws + OFF_WSPATT);
    u16* WrefT  = (u16*)(ws + OFF_WREFT);
    u16* WattT  = (u16*)(ws + OFF_WATTT);
    u16* WgT    = (u16*)(ws + OFF_WGT);
    u16* Ppb    = (u16*)(ws + OFF_PP);
    u16* Pob    = (u16*)(ws + OFF_PO);
    u16* Pcb    = (u16*)(ws + OFF_PC);
    float* adjw = (float*)(ws + OFF_ADJ);
    float* Hp   = (float*)(ws + OFF_HP);
    float* HoF  = (float*)(ws + OFF_HOF);
    float* Yh   = (float*)(ws + OFF_YH);
    float* Zo   = (float*)(ws + OFF_ZO);
    u16* WvisT2 = (u16*)(ws + OFF_WVIST2);
    u16* WhoT2  = (u16*)(ws + OFF_WHOT2);
    u16* WohT2  = (u16*)(ws + OFF_WOHT2);
    u16* peoB   = (u16*)(ws + OFF_PEOB);
    u16* objB   = (u16*)(ws + OFF_OBJB);
    u16* ctxB   = (u16*)(ws + OFF_CTXB);
    u16* spatB  = (u16*)(ws + OFF_SPATB);

    float* outI   = (float*)d_out;        // i_ho   [16384]
    float* outRef = outI + 16384;         // p_ref  [16384,29]
    float* outAtt = outI + 491520;        // p_att  [16384,29]
    float* outG   = outI + 966656;        // p_graph[16384,29]

    hipMemsetAsync(ws + ZERO_OFF, 0, ZERO_LEN, stream);

    prep_all<<<1408, 256, 0, stream>>>(people, objects, context, spatial,
        Wvis_w, Who_w, Woh_w, Wspat_w, Wref_w, Watt_w, Wg_w,
        peoB, objB, ctxB, spatB, WvisT2, WhoT2, WohT2,
        WspatT, WrefT, WattT, WgT);

    fused_gemms<<<888, 256, 0, stream>>>(peoB, objB, ctxB, WvisT2,
        WhoT2, Who_b, WohT2, Woh_b, WgT,
        Ppb, Pob, Pcb, Yh, Zo, Hp, HoF);

    mega<<<512, 256, 0, stream>>>(spatB, WspatT, Wspat_b,
                                  Ppb, Pob, Pcb, Wvis_b,
                                  WrefT, Wref_b, WattT, Watt_b,
                                  Wip_w, Wip_b,
                                  outI, outRef, outAtt, adjw);

    pgraph2<<<64, 256, 0, stream>>>(adjw, Hp, HoF, Yh, Zo, Wg_b, outG);
}